// Round 8
// baseline (303.199 us; speedup 1.0000x reference)
//
#include <hip/hip_runtime.h>
#include <hip/hip_bf16.h>
#include <stdint.h>

typedef __bf16 bf16x8 __attribute__((ext_vector_type(8)));
typedef __bf16 bf16x4 __attribute__((ext_vector_type(4)));
typedef float f32x4 __attribute__((ext_vector_type(4)));

__device__ __forceinline__ void gload_lds16(const __bf16* g, __bf16* l) {
  __builtin_amdgcn_global_load_lds(
      (const __attribute__((address_space(1))) void*)g,
      (__attribute__((address_space(3))) void*)l, 16, 0, 0);
}

// ---------------------------------------------------------------------------
// fp32 -> bf16 convert for the 4 weight matrices (contiguous dst)
// ---------------------------------------------------------------------------
__global__ __launch_bounds__(256) void cvt4_kernel(const float* __restrict__ s0,
                                                   const float* __restrict__ s1,
                                                   const float* __restrict__ s2,
                                                   const float* __restrict__ s3,
                                                   __bf16* __restrict__ dst) {
  int i = blockIdx.x * 256 + threadIdx.x;
  const float* srcs[4] = {s0, s1, s2, s3};
  int m = i >> 18;
  dst[i] = (__bf16)srcs[m][i & 262143];
}

__global__ __launch_bounds__(256) void biascat_kernel(const float* __restrict__ bq,
                                                      const float* __restrict__ bk,
                                                      float* __restrict__ bqk) {
  int i = blockIdx.x * 256 + threadIdx.x;  // 1024
  bqk[i] = (i < 512) ? bq[i] : bk[i - 512];
}

// ---------------------------------------------------------------------------
// GN1a: stream x fp32 once; write xbf + per-(b,g,slice) partial sums.
// ---------------------------------------------------------------------------
__global__ __launch_bounds__(256) void gn1a_kernel(const float* __restrict__ x,
                                                   __bf16* __restrict__ xbf,
                                                   float2* __restrict__ part) {
  const int tid = threadIdx.x;
  const size_t base4 = ((size_t)blockIdx.x * 8192) >> 2;
  const float4* x4 = (const float4*)x;
  bf16x4* o4 = (bf16x4*)xbf;

  float s1 = 0.f, s2 = 0.f;
#pragma unroll
  for (int j = 0; j < 8; ++j) {
    float4 t = x4[base4 + tid + j * 256];
    s1 += t.x + t.y + t.z + t.w;
    s2 += t.x * t.x + t.y * t.y + t.z * t.z + t.w * t.w;
    bf16x4 o;
    o[0] = (__bf16)t.x; o[1] = (__bf16)t.y; o[2] = (__bf16)t.z; o[3] = (__bf16)t.w;
    o4[base4 + tid + j * 256] = o;
  }
#pragma unroll
  for (int off = 32; off; off >>= 1) {
    s1 += __shfl_xor(s1, off);
    s2 += __shfl_xor(s2, off);
  }
  __shared__ float r1[4], r2[4];
  if ((tid & 63) == 0) { r1[tid >> 6] = s1; r2[tid >> 6] = s2; }
  __syncthreads();
  if (tid == 0)
    part[blockIdx.x] = float2{r1[0] + r1[1] + r1[2] + r1[3],
                              r2[0] + r2[1] + r2[2] + r2[3]};
}

__global__ __launch_bounds__(512) void gn1b_kernel(const float2* __restrict__ part,
                                                   const float* __restrict__ gamma,
                                                   const float* __restrict__ beta,
                                                   float2* __restrict__ gmbt) {
  const int b = blockIdx.x;
  const int t = threadIdx.x;
  __shared__ float sm[32], si[32];
  if (t < 32) {
    float s1 = 0.f, s2 = 0.f;
#pragma unroll
    for (int j = 0; j < 8; ++j) {
      float2 p = part[(b * 32 + t) * 8 + j];
      s1 += p.x; s2 += p.y;
    }
    const float mean = s1 * (1.f / 65536.f);
    const float var = s2 * (1.f / 65536.f) - mean * mean;
    sm[t] = mean;
    si[t] = rsqrtf(var + 1e-6f);
  }
  __syncthreads();
  const int g = t >> 4;
  const float gm = gamma[t] * si[g];
  gmbt[b * 512 + t] = float2{gm, beta[t] - sm[g] * gm};
}

// ---------------------------------------------------------------------------
// GN2: normalize + transpose. xbf [b,c,n] -> hnT [b,n,c] bf16.
// ---------------------------------------------------------------------------
__global__ __launch_bounds__(256) void gn2_kernel(const __bf16* __restrict__ xbf,
                                                  const float2* __restrict__ gmbt,
                                                  __bf16* __restrict__ hnT) {
  const int b = blockIdx.z;
  const int c0 = blockIdx.y * 64;
  const int n0 = blockIdx.x * 64;
  const int t = threadIdx.x;
  __shared__ __bf16 tile[64][72];

  {
    const int row = t >> 2;
    const int col = (t & 3) * 16;
    const __bf16* src = xbf + ((size_t)(b * 512 + c0 + row)) * 4096 + n0 + col;
    bf16x8 u0 = *(const bf16x8*)src;
    bf16x8 u1 = *(const bf16x8*)(src + 8);
    *(bf16x8*)&tile[row][col] = u0;
    *(bf16x8*)&tile[row][col + 8] = u1;
  }
  __syncthreads();
  {
    const int nrow = t >> 2;
    const int cc = (t & 3) * 16;
    bf16x8 o0, o1;
#pragma unroll
    for (int j = 0; j < 16; ++j) {
      const int c = c0 + cc + j;
      float2 s = gmbt[b * 512 + c];
      float val = (float)tile[cc + j][nrow] * s.x + s.y;
      if (j < 8) o0[j] = (__bf16)val; else o1[j - 8] = (__bf16)val;
    }
    __bf16* dst = hnT + ((size_t)b * 4096 + n0 + nrow) * 512 + c0 + cc;
    *(bf16x8*)dst = o0;
    *(bf16x8*)(dst + 8) = o1;
  }
}

// ---------------------------------------------------------------------------
// rowsum+inv over P' rows (bf16, length 4096): inv[r] = 1/sum(P'[r,:]).
// One wave per row, 4 waves/block.
// ---------------------------------------------------------------------------
__global__ __launch_bounds__(256) void rowsum_inv_kernel(const __bf16* __restrict__ P,
                                                         float* __restrict__ inv) {
  const int r = blockIdx.x * 4 + (threadIdx.x >> 6);
  const int lane = threadIdx.x & 63;
  const bf16x8* rp = (const bf16x8*)(P + (size_t)r * 4096);
  float s = 0.f;
#pragma unroll
  for (int j = 0; j < 8; ++j) {
    bf16x8 v = rp[lane + j * 64];
#pragma unroll
    for (int e = 0; e < 8; ++e) s += (float)v[e];
  }
#pragma unroll
  for (int off = 32; off; off >>= 1) s += __shfl_xor(s, off);
  if (lane == 0) inv[r] = 1.0f / s;
}

// ---------------------------------------------------------------------------
// Ring-6 8-wave MFMA GEMM engine (T1+T2+T3+T4+T5, deepened pipeline).
// D[m,n] = f( scale * sum_k A[m,k]*B[n,k] ); bf16 in/out, f32 acc.
// BM=256, BN=128 fixed. BK=32 k-slots, ring of SIX LDS slots per operand
// (lookahead 4 staged slots in flight ~= 72-96 KB/CU) — fixes the ring-4
// latency starvation (24 KB in flight vs 900cy HBM latency).
// Waves 2x4: wave = 128 rows x 32 cols; per phase 8 MFMA (nh in {0,1}).
// Ledger: 3 loads/slot (2 A + 1 B). Main loop vmcnt(12) = slots s+2..s+5
// outstanding => slot s+1 complete before its first read. Tail: 9/6/3/0.
// EEXP: D = exp(val) (no-max softmax numerator; scores bounded ~N(0,1)).
// RSCALE: D = val * rowinv[row]. BIAS: + bias[col].
// Epilogue: per-wave LDS bounce (aliases dead ring) -> bf16x8 stores.
// Requires M%256==0, N%128==0, KC%32==0, KC/32 >= 6.
// ---------------------------------------------------------------------------
template <int BIAS, int EEXP, int RSCALE, int KC>
__global__ __launch_bounds__(512) void gemm6r_kernel(
    const __bf16* __restrict__ A, int lda, long long sA,
    const __bf16* __restrict__ Bm, int ldb, long long sB,
    __bf16* __restrict__ Out, int ldo, long long sO,
    const float* __restrict__ bias, const float* __restrict__ rowinv,
    float scale) {
  constexpr int ASLOT = 8192;   // 256x32 elems
  constexpr int BSLOT = 4096;   // 128x32 elems
  constexpr int WN = 32;
  constexpr int BST = WN + 8;
  __shared__ __bf16 sm[6 * ASLOT + 6 * BSLOT];  // 144 KiB
  __bf16* smB = sm + 6 * ASLOT;

  // T1: XCD-chunked swizzle (all grids used are multiples of 8)
  const int gx = gridDim.x, gxy = gx * gridDim.y;
  const int nwg = gxy * gridDim.z;
  int bid = blockIdx.x + gx * blockIdx.y + gxy * blockIdx.z;
  bid = (bid & 7) * (nwg >> 3) + (bid >> 3);
  const int bz = bid / gxy;
  const int rem = bid - bz * gxy;
  const int by = rem / gx, bx = rem - by * gx;
  const int tm0 = by * 256, tn0 = bx * 128;

  const int t = threadIdx.x;
  const int lane = t & 63, wid = t >> 6;
  const int wr = wid >> 2, wc = wid & 3;

  const __bf16* Az = A + (size_t)bz * sA;
  const __bf16* Bz = Bm + (size_t)bz * sB;

  // staging sources (pre-swizzled col so linear LDS + swizzled read = identity)
  const int scol = ((t & 3) * 8) ^ (((t >> 3) & 3) * 8);
  const __bf16* gA0 = Az + (size_t)(tm0 + (t >> 2)) * lda + scol;
  const __bf16* gA1 = gA0 + (size_t)128 * lda;
  const __bf16* gB0 = Bz + (size_t)(tn0 + (t >> 2)) * ldb + scol;
  __bf16* dA = sm + t * 8;
  __bf16* dB = smB + t * 8;

  auto stageA = [&](int ks, int sl) {
    gload_lds16(gA0 + (size_t)ks * 32, dA + sl * ASLOT);
    gload_lds16(gA1 + (size_t)ks * 32, dA + sl * ASLOT + 4096);
  };
  auto stageB = [&](int ks, int sl) {
    gload_lds16(gB0 + (size_t)ks * 32, dB + sl * BSLOT);
  };

  // swizzled fragment read bases
  const int lr = lane & 15;
  const int kb = ((lane >> 4) * 16) ^ ((lr & 6) << 3);  // byte off within row
  const __bf16* rdA = sm + (((wr * 128 + lr) * 64 + kb) >> 1);
  const __bf16* rdB = smB + (((wc * WN + lr) * 64 + kb) >> 1);

  f32x4 acc[8][2];
#pragma unroll
  for (int m = 0; m < 8; ++m) {
    acc[m][0] = f32x4{0.f, 0.f, 0.f, 0.f};
    acc[m][1] = f32x4{0.f, 0.f, 0.f, 0.f};
  }
  bf16x8 av[8];

  auto rdAfr = [&](int sl) {
#pragma unroll
    for (int m = 0; m < 8; ++m)
      av[m] = *(const bf16x8*)(rdA + sl * ASLOT + m * 512);
  };
  auto mmaPh = [&](int sl, int nh) {
    bf16x8 bv = *(const bf16x8*)(rdB + sl * BSLOT + nh * 512);
    __builtin_amdgcn_s_barrier();
    __builtin_amdgcn_s_setprio(1);
#pragma unroll
    for (int m = 0; m < 8; ++m)
      acc[m][nh] = __builtin_amdgcn_mfma_f32_16x16x32_bf16(av[m], bv, acc[m][nh], 0, 0, 0);
    __builtin_amdgcn_s_setprio(0);
    __builtin_amdgcn_s_barrier();
  };

  constexpr int TOT = KC / 32;  // k-slots, >= 6

  // prologue: stage slots 0..4 in consumption order (15 loads);
  // vmcnt(12) -> slot 0's 3 loads complete.
  stageA(0, 0); stageB(0, 0);
  stageA(1, 1); stageB(1, 1);
  stageA(2, 2); stageB(2, 2);
  stageA(3, 3); stageB(3, 3);
  stageA(4, 4); stageB(4, 4);
  asm volatile("s_waitcnt vmcnt(12)" ::: "memory");
  __builtin_amdgcn_s_barrier();

  int cs = 0;  // consume slot
  int ss = 5;  // stage slot
#pragma unroll 1
  for (int s = 0; s < TOT - 5; ++s) {
    rdAfr(cs); stageA(s + 5, ss);   mmaPh(cs, 0);
    stageB(s + 5, ss);
    asm volatile("s_waitcnt vmcnt(12)" ::: "memory");
    mmaPh(cs, 1);
    cs = (cs == 5) ? 0 : cs + 1;
    ss = (ss == 5) ? 0 : ss + 1;
  }
  // tail: 5 remaining slots, draining ledger 9/6/3/0
  rdAfr(cs); mmaPh(cs, 0);
  asm volatile("s_waitcnt vmcnt(9)" ::: "memory");
  mmaPh(cs, 1); cs = (cs == 5) ? 0 : cs + 1;
  rdAfr(cs); mmaPh(cs, 0);
  asm volatile("s_waitcnt vmcnt(6)" ::: "memory");
  mmaPh(cs, 1); cs = (cs == 5) ? 0 : cs + 1;
  rdAfr(cs); mmaPh(cs, 0);
  asm volatile("s_waitcnt vmcnt(3)" ::: "memory");
  mmaPh(cs, 1); cs = (cs == 5) ? 0 : cs + 1;
  rdAfr(cs); mmaPh(cs, 0);
  asm volatile("s_waitcnt vmcnt(0)" ::: "memory");
  mmaPh(cs, 1); cs = (cs == 5) ? 0 : cs + 1;
  rdAfr(cs); mmaPh(cs, 0);
  mmaPh(cs, 1);

  // Epilogue. D mapping col=lane&15, row=(lane>>4)*4+reg (verified m89).
  // Bounce through wave-private LDS (aliases dead ring region).
  __bf16* bnc = sm + wid * 16 * BST;
  const int q4 = (lane >> 4) * 4;
  const int row0 = tm0 + wr * 128;
  const int wn = tn0 + wc * WN;
  float bcol[2];
  bcol[0] = BIAS ? bias[wn + lr] : 0.f;
  bcol[1] = BIAS ? bias[wn + 16 + lr] : 0.f;
#pragma unroll
  for (int m = 0; m < 8; ++m) {
    float ri[4];
    if constexpr (RSCALE) {
#pragma unroll
      for (int r = 0; r < 4; ++r)
        ri[r] = rowinv[(size_t)bz * 4096 + row0 + m * 16 + q4 + r];
    }
#pragma unroll
    for (int n = 0; n < 2; ++n)
#pragma unroll
      for (int r = 0; r < 4; ++r) {
        float val = acc[m][n][r] * scale + bcol[n];
        if constexpr (EEXP) val = exp2f(val * 1.44269504f);
        if constexpr (RSCALE) val *= ri[r];
        bnc[(q4 + r) * BST + n * 16 + lr] = (__bf16)val;
      }
    const int rr = lane >> 2, c8 = (lane & 3) * 8;
    bf16x8 v0 = *(const bf16x8*)&bnc[rr * BST + c8];
    __bf16* op = Out + (size_t)bz * sO +
                 (size_t)(row0 + m * 16 + rr) * ldo + wn + c8;
    *(bf16x8*)op = v0;
  }
}

// ---------------------------------------------------------------------------
// 2-phase 128x128 GEMM (skinny shapes: v-proj, out-proj).
// EPI: 0 = bf16 out, 1 = f32 out, 2 = f32 out * xmul(bf16). BIAS: 0/1(col)/2(row).
// ---------------------------------------------------------------------------
template <int EPI, int BIAS>
__global__ __launch_bounds__(256) void gemm_lds_kernel(
    const __bf16* __restrict__ A, int lda, long long sA,
    const __bf16* __restrict__ Bm, int ldb, long long sB,
    void* __restrict__ Out, int ldo, long long sO,
    const float* __restrict__ bias, const __bf16* __restrict__ xmul,
    long long sX, float scale, int K) {
  __shared__ __bf16 sTa[2][128 * 32];
  __shared__ __bf16 sTb[2][128 * 32];

  const int gx = gridDim.x, gxy = gx * gridDim.y;
  const int nwg = gxy * gridDim.z;
  int bid = blockIdx.x + gx * blockIdx.y + gxy * blockIdx.z;
  if ((nwg & 7) == 0) bid = (bid & 7) * (nwg >> 3) + (bid >> 3);
  const int bz = bid / gxy;
  const int rem = bid - bz * gxy;
  const int by = rem / gx;
  const int bx = rem - by * gx;

  const int tid = threadIdx.x;
  const int lane = tid & 63;
  const int wid = tid >> 6;
  const int wr = wid >> 1, wc = wid & 1;
  const int tm0 = by * 128, tn0 = bx * 128;
  const int lr = lane & 15, lk = (lane >> 4) * 8;

  const int ch0 = wid * 2;
  const int srow = lane >> 2;
  const int scol = (lane & 3) * 8;
  const __bf16* gA0 = A + (size_t)bz * sA + (size_t)(tm0 + ch0 * 16 + srow) * lda + scol;
  const __bf16* gB0 = Bm + (size_t)bz * sB + (size_t)(tn0 + ch0 * 16 + srow) * ldb + scol;
  const size_t stepA = (size_t)16 * lda, stepB = (size_t)16 * ldb;

  f32x4 acc[4][4];
#pragma unroll
  for (int i = 0; i < 4; ++i)
#pragma unroll
    for (int j = 0; j < 4; ++j) acc[i][j] = f32x4{0.f, 0.f, 0.f, 0.f};

  const int T = K >> 5;
  gload_lds16(gA0, &sTa[0][ch0 * 512]);
  gload_lds16(gA0 + stepA, &sTa[0][ch0 * 512 + 512]);
  gload_lds16(gB0, &sTb[0][ch0 * 512]);
  gload_lds16(gB0 + stepB, &sTb[0][ch0 * 512 + 512]);

  for (int tt = 0; tt < T; ++tt) {
    __syncthreads();
    const int cur = tt & 1;
    if (tt + 1 < T) {
      const __bf16* a = gA0 + (size_t)(tt + 1) * 32;
      const __bf16* b = gB0 + (size_t)(tt + 1) * 32;
      gload_lds16(a, &sTa[cur ^ 1][ch0 * 512]);
      gload_lds16(a + stepA, &sTa[cur ^ 1][ch0 * 512 + 512]);
      gload_lds16(b, &sTb[cur ^ 1][ch0 * 512]);
      gload_lds16(b + stepB, &sTb[cur ^ 1][ch0 * 512 + 512]);
    }
    const __bf16* fa = &sTa[cur][(wr * 64 + lr) * 32 + lk];
    const __bf16* fb = &sTb[cur][(wc * 64 + lr) * 32 + lk];
    bf16x8 a[4], b[4];
#pragma unroll
    for (int i = 0; i < 4; ++i) a[i] = *(const bf16x8*)(fa + i * 512);
#pragma unroll
    for (int j = 0; j < 4; ++j) b[j] = *(const bf16x8*)(fb + j * 512);
#pragma unroll
    for (int i = 0; i < 4; ++i)
#pragma unroll
      for (int j = 0; j < 4; ++j)
        acc[i][j] = __builtin_amdgcn_mfma_f32_16x16x32_bf16(a[i], b[j], acc[i][j], 0, 0, 0);
  }

  const int wm = tm0 + wr * 64, wn = tn0 + wc * 64;
#pragma unroll
  for (int i = 0; i < 4; ++i) {
#pragma unroll
    for (int r = 0; r < 4; ++r) {
      const int row = wm + i * 16 + (lane >> 4) * 4 + r;
#pragma unroll
      for (int j = 0; j < 4; ++j) {
        const int col = wn + j * 16 + lr;
        float val = acc[i][j][r] * scale;
        if (BIAS == 1) val += bias[col];
        if (BIAS == 2) val += bias[row];
        const size_t off = (size_t)bz * sO + (size_t)row * ldo + col;
        if (EPI == 0) {
          ((__bf16*)Out)[off] = (__bf16)val;
        } else if (EPI == 1) {
          ((float*)Out)[off] = val;
        } else {
          ((float*)Out)[off] = (float)xmul[(size_t)bz * sX + (size_t)row * ldo + col] * val;
        }
      }
    }
  }
}

// ---------------------------------------------------------------------------
// Workspace (batched ~194 MiB):
//   S 128MB @0 (hnT aliases first 16) | qkT 32MB @128 (a2T alias) | v @160
//   xbf @176 | wB @192 | misc @194. rowInv (64 KB f32) lives in d_out
//   scratch, overwritten by the final out-proj.
// ---------------------------------------------------------------------------
extern "C" void kernel_launch(void* const* d_in, const int* in_sizes, int n_in,
                              void* d_out, int out_size, void* d_ws, size_t ws_size,
                              hipStream_t stream) {
  const int C = 512, N = 4096;
  const float* x = (const float*)d_in[0];
  const float* gng = (const float*)d_in[1];
  const float* gnb = (const float*)d_in[2];
  const float* wq = (const float*)d_in[3];
  const float* bq = (const float*)d_in[4];
  const float* wk = (const float*)d_in[5];
  const float* bk = (const float*)d_in[6];
  const float* wv = (const float*)d_in[7];
  const float* bv = (const float*)d_in[8];
  const float* wo = (const float*)d_in[9];
  const float* bo = (const float*)d_in[10];

  char* ws = (char*)d_ws;
  const size_t MB = 1ull << 20;
  const long long NC = (long long)N * C;
  const long long NN = (long long)N * N;
  const long long NQK = (long long)N * 1024;
  const bool batched = ws_size >= 194 * MB + 32768;

  __bf16 *S, *qkT, *a2T, *v, *xbf, *wqB;
  char* misc;
  if (batched) {
    S   = (__bf16*)(ws);
    qkT = (__bf16*)(ws + 128 * MB);
    a2T = qkT;
    v   = (__bf16*)(ws + 160 * MB);
    xbf = (__bf16*)(ws + 176 * MB);
    wqB = (__bf16*)(ws + 192 * MB);
    misc = ws + 194 * MB;
  } else {
    S   = (__bf16*)(ws);
    qkT = (__bf16*)(ws + 32 * MB);
    a2T = (__bf16*)(ws + 64 * MB);
    v   = (__bf16*)(ws + 80 * MB);
    xbf = (__bf16*)(ws + 96 * MB);
    wqB = (__bf16*)(ws + 112 * MB);
    misc = ws + 114 * MB;
  }
  __bf16* hnT = (__bf16*)ws;  // aliases S; dead before QK writes S
  __bf16* wvB = wqB + 2 * 262144;
  __bf16* woB = wvB + 262144;
  float* bqk   = (float*)misc;
  float2* gmbt = (float2*)(misc + 4096);
  float2* part = (float2*)(misc + 20480);
  float* rowInv = (float*)d_out;  // scratch in d_out, overwritten at the end

  const float scl = 0.044194173824159216f;  // 512^-0.5

  cvt4_kernel<<<4096, 256, 0, stream>>>(wq, wk, wv, wo, wqB);
  biascat_kernel<<<4, 256, 0, stream>>>(bq, bk, bqk);
  gn1a_kernel<<<1024, 256, 0, stream>>>(x, xbf, part);
  gn1b_kernel<<<4, 512, 0, stream>>>(part, gng, gnb, gmbt);
  gn2_kernel<<<dim3(64, 8, 4), 256, 0, stream>>>(xbf, gmbt, hnT);

  // fused q,k projection: qkT[b,n,0:512]=q, [512:1024]=k
  gemm6r_kernel<1, 0, 0, 512><<<dim3(8, 16, 4), 512, 0, stream>>>(
      hnT, C, NC, wqB, C, 0, qkT, 1024, NQK, bqk, nullptr, 1.f);
  // v[b,c,n]
  gemm_lds_kernel<0, 2><<<dim3(32, 4, 4), 256, 0, stream>>>(
      wvB, C, 0, hnT, C, NC, v, N, NC, bv, nullptr, 0, 1.f, C);

  if (batched) {
    // QK: S = exp(scl * q.k)  (unnormalized softmax numerator, bf16)
    gemm6r_kernel<0, 1, 0, 512><<<dim3(32, 16, 4), 512, 0, stream>>>(
        qkT, 1024, NQK, qkT + 512, 1024, NQK, S, N, NN, nullptr, nullptr, scl);
    rowsum_inv_kernel<<<4096, 256, 0, stream>>>(S, rowInv);
    // PV: a2T[i,c] = inv[i] * sum_j S[i,j] * v[c,j]
    gemm6r_kernel<0, 0, 1, 4096><<<dim3(4, 16, 4), 512, 0, stream>>>(
        S, N, NN, v, N, NC, a2T, C, NC, nullptr, rowInv, 1.f);
  } else {
    for (int b = 0; b < 4; ++b) {
      gemm6r_kernel<0, 1, 0, 512><<<dim3(32, 16, 1), 512, 0, stream>>>(
          qkT + (size_t)b * NQK, 1024, 0, qkT + (size_t)b * NQK + 512, 1024, 0,
          S, N, 0, nullptr, nullptr, scl);
      rowsum_inv_kernel<<<1024, 256, 0, stream>>>(S, rowInv);
      gemm6r_kernel<0, 0, 1, 4096><<<dim3(4, 16, 1), 512, 0, stream>>>(
          S, N, 0, v + (size_t)b * NC, N, 0, a2T + (size_t)b * NC, C, 0,
          nullptr, rowInv, 1.f);
    }
  }

  // out[b,c,n] = xbf[b,c,n] * (sum_k wo[c,k] * a2T[b,n,k] + bo[c])
  gemm_lds_kernel<2, 2><<<dim3(32, 4, 4), 256, 0, stream>>>(
      woB, C, 0, a2T, C, NC, (float*)d_out, N, NC, bo, xbf, NC, 1.f, C);
}

// Round 9
// 289.145 us; speedup vs baseline: 1.0486x; 1.0486x over previous
//
#include <hip/hip_runtime.h>
#include <hip/hip_bf16.h>
#include <stdint.h>

typedef __bf16 bf16x8 __attribute__((ext_vector_type(8)));
typedef __bf16 bf16x4 __attribute__((ext_vector_type(4)));
typedef float f32x4 __attribute__((ext_vector_type(4)));

__device__ __forceinline__ void gload_lds16(const __bf16* g, __bf16* l) {
  __builtin_amdgcn_global_load_lds(
      (const __attribute__((address_space(1))) void*)g,
      (__attribute__((address_space(3))) void*)l, 16, 0, 0);
}

// ---------------------------------------------------------------------------
// fp32 -> bf16 convert for the 4 weight matrices (contiguous dst)
// ---------------------------------------------------------------------------
__global__ __launch_bounds__(256) void cvt4_kernel(const float* __restrict__ s0,
                                                   const float* __restrict__ s1,
                                                   const float* __restrict__ s2,
                                                   const float* __restrict__ s3,
                                                   __bf16* __restrict__ dst) {
  int i = blockIdx.x * 256 + threadIdx.x;
  const float* srcs[4] = {s0, s1, s2, s3};
  int m = i >> 18;
  dst[i] = (__bf16)srcs[m][i & 262143];
}

__global__ __launch_bounds__(256) void biascat_kernel(const float* __restrict__ bq,
                                                      const float* __restrict__ bk,
                                                      float* __restrict__ bqk) {
  int i = blockIdx.x * 256 + threadIdx.x;  // 1024
  bqk[i] = (i < 512) ? bq[i] : bk[i - 512];
}

// ---------------------------------------------------------------------------
// GN1a: stream x fp32 once; write xbf + per-(b,g,slice) partial sums.
// ---------------------------------------------------------------------------
__global__ __launch_bounds__(256) void gn1a_kernel(const float* __restrict__ x,
                                                   __bf16* __restrict__ xbf,
                                                   float2* __restrict__ part) {
  const int tid = threadIdx.x;
  const size_t base4 = ((size_t)blockIdx.x * 8192) >> 2;
  const float4* x4 = (const float4*)x;
  bf16x4* o4 = (bf16x4*)xbf;

  float s1 = 0.f, s2 = 0.f;
#pragma unroll
  for (int j = 0; j < 8; ++j) {
    float4 t = x4[base4 + tid + j * 256];
    s1 += t.x + t.y + t.z + t.w;
    s2 += t.x * t.x + t.y * t.y + t.z * t.z + t.w * t.w;
    bf16x4 o;
    o[0] = (__bf16)t.x; o[1] = (__bf16)t.y; o[2] = (__bf16)t.z; o[3] = (__bf16)t.w;
    o4[base4 + tid + j * 256] = o;
  }
#pragma unroll
  for (int off = 32; off; off >>= 1) {
    s1 += __shfl_xor(s1, off);
    s2 += __shfl_xor(s2, off);
  }
  __shared__ float r1[4], r2[4];
  if ((tid & 63) == 0) { r1[tid >> 6] = s1; r2[tid >> 6] = s2; }
  __syncthreads();
  if (tid == 0)
    part[blockIdx.x] = float2{r1[0] + r1[1] + r1[2] + r1[3],
                              r2[0] + r2[1] + r2[2] + r2[3]};
}

__global__ __launch_bounds__(512) void gn1b_kernel(const float2* __restrict__ part,
                                                   const float* __restrict__ gamma,
                                                   const float* __restrict__ beta,
                                                   float2* __restrict__ gmbt) {
  const int b = blockIdx.x;
  const int t = threadIdx.x;
  __shared__ float sm[32], si[32];
  if (t < 32) {
    float s1 = 0.f, s2 = 0.f;
#pragma unroll
    for (int j = 0; j < 8; ++j) {
      float2 p = part[(b * 32 + t) * 8 + j];
      s1 += p.x; s2 += p.y;
    }
    const float mean = s1 * (1.f / 65536.f);
    const float var = s2 * (1.f / 65536.f) - mean * mean;
    sm[t] = mean;
    si[t] = rsqrtf(var + 1e-6f);
  }
  __syncthreads();
  const int g = t >> 4;
  const float gm = gamma[t] * si[g];
  gmbt[b * 512 + t] = float2{gm, beta[t] - sm[g] * gm};
}

// ---------------------------------------------------------------------------
// GN2: normalize + transpose. xbf [b,c,n] -> hnT [b,n,c] bf16.
// ---------------------------------------------------------------------------
__global__ __launch_bounds__(256) void gn2_kernel(const __bf16* __restrict__ xbf,
                                                  const float2* __restrict__ gmbt,
                                                  __bf16* __restrict__ hnT) {
  const int b = blockIdx.z;
  const int c0 = blockIdx.y * 64;
  const int n0 = blockIdx.x * 64;
  const int t = threadIdx.x;
  __shared__ __bf16 tile[64][72];

  {
    const int row = t >> 2;
    const int col = (t & 3) * 16;
    const __bf16* src = xbf + ((size_t)(b * 512 + c0 + row)) * 4096 + n0 + col;
    bf16x8 u0 = *(const bf16x8*)src;
    bf16x8 u1 = *(const bf16x8*)(src + 8);
    *(bf16x8*)&tile[row][col] = u0;
    *(bf16x8*)&tile[row][col + 8] = u1;
  }
  __syncthreads();
  {
    const int nrow = t >> 2;
    const int cc = (t & 3) * 16;
    bf16x8 o0, o1;
#pragma unroll
    for (int j = 0; j < 16; ++j) {
      const int c = c0 + cc + j;
      float2 s = gmbt[b * 512 + c];
      float val = (float)tile[cc + j][nrow] * s.x + s.y;
      if (j < 8) o0[j] = (__bf16)val; else o1[j - 8] = (__bf16)val;
    }
    __bf16* dst = hnT + ((size_t)b * 4096 + n0 + nrow) * 512 + c0 + cc;
    *(bf16x8*)dst = o0;
    *(bf16x8*)(dst + 8) = o1;
  }
}

// ---------------------------------------------------------------------------
// rowsum+inv over P' rows (bf16, length 4096): inv[r] = 1/sum(P'[r,:]).
// One wave per row, 4 waves/block.
// ---------------------------------------------------------------------------
__global__ __launch_bounds__(256) void rowsum_inv_kernel(const __bf16* __restrict__ P,
                                                         float* __restrict__ inv) {
  const int r = blockIdx.x * 4 + (threadIdx.x >> 6);
  const int lane = threadIdx.x & 63;
  const bf16x8* rp = (const bf16x8*)(P + (size_t)r * 4096);
  float s = 0.f;
#pragma unroll
  for (int j = 0; j < 8; ++j) {
    bf16x8 v = rp[lane + j * 64];
#pragma unroll
    for (int e = 0; e < 8; ++e) s += (float)v[e];
  }
#pragma unroll
  for (int off = 32; off; off >>= 1) s += __shfl_xor(s, off);
  if (lane == 0) inv[r] = 1.0f / s;
}

// ---------------------------------------------------------------------------
// gemm4w: 4-wave 128x128 MFMA engine — counted-vmcnt ring-4 + T2 swizzle +
// 2 resident blocks/CU (64 KiB LDS). The TLP+pipeline combination:
// round-3 (2-phase) had TLP but drained vmcnt(0); round-6 (8-phase) had the
// counted pipeline but 1 block/CU. This has both.
// D[m,n] = f( scale * sum_k A[m,k]*B[n,k] ); bf16 in/out, f32 acc.
// Waves 2x2, wave tile 64x64 (4x4 frags, 16 MFMA per BK=32 slot between one
// barrier pair). Ledger: 4 loads/slot, lookahead 3 slots; steady vmcnt(8)
// (slots s+2,s+3 in flight, slot s+1 complete); tail 4/0.
// EEXP: D = exp(val) (no-max softmax numerator; scores bounded ~N(0,1)).
// RSCALE: D = val * rowinv[row]. BIAS: + bias[col].
// Requires M%128==0, N%128==0, KC%32==0, KC/32 >= 4, grid multiple of 8.
// ---------------------------------------------------------------------------
template <int BIAS, int EEXP, int RSCALE, int KC>
__global__ __launch_bounds__(256) void gemm4w_kernel(
    const __bf16* __restrict__ A, int lda, long long sA,
    const __bf16* __restrict__ Bm, int ldb, long long sB,
    __bf16* __restrict__ Out, int ldo, long long sO,
    const float* __restrict__ bias, const float* __restrict__ rowinv,
    float scale) {
  constexpr int SLOT = 4096;   // 128x32 elems
  constexpr int BST = 72;      // bounce row stride
  __shared__ __bf16 sm[8 * SLOT];  // 64 KiB: A ring [0..4), B ring [4..8)
  __bf16* smB = sm + 4 * SLOT;

  // T1: XCD-chunked swizzle
  const int gx = gridDim.x, gxy = gx * gridDim.y;
  const int nwg = gxy * gridDim.z;
  int bid = blockIdx.x + gx * blockIdx.y + gxy * blockIdx.z;
  bid = (bid & 7) * (nwg >> 3) + (bid >> 3);
  const int bz = bid / gxy;
  const int rem = bid - bz * gxy;
  const int by = rem / gx, bx = rem - by * gx;
  const int tm0 = by * 128, tn0 = bx * 128;

  const int t = threadIdx.x;
  const int lane = t & 63, wid = t >> 6;
  const int wr = wid >> 1, wc = wid & 1;

  const __bf16* Az = A + (size_t)bz * sA;
  const __bf16* Bz = Bm + (size_t)bz * sB;

  // staging: thread t covers row t>>2 (+64 on 2nd pass), pre-swizzled chunk
  const int scol = ((t & 3) * 8) ^ (((t >> 3) & 3) * 8);
  const __bf16* gA0 = Az + (size_t)(tm0 + (t >> 2)) * lda + scol;
  const __bf16* gA1 = gA0 + (size_t)64 * lda;
  const __bf16* gB0 = Bz + (size_t)(tn0 + (t >> 2)) * ldb + scol;
  const __bf16* gB1 = gB0 + (size_t)64 * ldb;
  __bf16* dA = sm + t * 8;
  __bf16* dB = smB + t * 8;

  auto stage = [&](int ks) {
    const int sl = ks & 3;
    gload_lds16(gA0 + (size_t)ks * 32, dA + sl * SLOT);
    gload_lds16(gA1 + (size_t)ks * 32, dA + sl * SLOT + 2048);
    gload_lds16(gB0 + (size_t)ks * 32, dB + sl * SLOT);
    gload_lds16(gB1 + (size_t)ks * 32, dB + sl * SLOT + 2048);
  };

  // swizzled fragment read bases (row stride 64 B)
  const int lr = lane & 15;
  const int kb = ((lane >> 4) * 16) ^ ((lr & 6) << 3);
  const __bf16* rdA = sm + (((wr * 64 + lr) * 64 + kb) >> 1);
  const __bf16* rdB = smB + (((wc * 64 + lr) * 64 + kb) >> 1);

  f32x4 acc[4][4];
#pragma unroll
  for (int i = 0; i < 4; ++i)
#pragma unroll
    for (int j = 0; j < 4; ++j) acc[i][j] = f32x4{0.f, 0.f, 0.f, 0.f};
  bf16x8 av[4], bv[4];

  auto rdfr = [&](int sl) {
#pragma unroll
    for (int m = 0; m < 4; ++m) av[m] = *(const bf16x8*)(rdA + sl * SLOT + m * 512);
#pragma unroll
    for (int n = 0; n < 4; ++n) bv[n] = *(const bf16x8*)(rdB + sl * SLOT + n * 512);
  };
  auto mma16 = [&] {
    __builtin_amdgcn_s_barrier();
    __builtin_amdgcn_s_setprio(1);
#pragma unroll
    for (int m = 0; m < 4; ++m)
#pragma unroll
      for (int n = 0; n < 4; ++n)
        acc[m][n] = __builtin_amdgcn_mfma_f32_16x16x32_bf16(av[m], bv[n], acc[m][n], 0, 0, 0);
    __builtin_amdgcn_s_setprio(0);
  };

  constexpr int TOT = KC / 32;  // >= 4

  // prologue: stage slots 0,1,2 (12 loads); vmcnt(8) -> slot 0 complete
  stage(0); stage(1); stage(2);
  asm volatile("s_waitcnt vmcnt(8)" ::: "memory");
  __builtin_amdgcn_s_barrier();

#pragma unroll 1
  for (int s = 0; s < TOT - 3; ++s) {
    rdfr(s & 3);
    stage(s + 3);
    mma16();
    asm volatile("s_waitcnt vmcnt(8)" ::: "memory");
    __builtin_amdgcn_s_barrier();
  }
  // tail: 3 slots left, ledger 4 / 0 / -
  rdfr((TOT - 3) & 3); mma16();
  asm volatile("s_waitcnt vmcnt(4)" ::: "memory");
  __builtin_amdgcn_s_barrier();
  rdfr((TOT - 2) & 3); mma16();
  asm volatile("s_waitcnt vmcnt(0)" ::: "memory");
  __builtin_amdgcn_s_barrier();
  rdfr((TOT - 1) & 3); mma16();
  __builtin_amdgcn_s_barrier();  // ring reads done before bounce aliases LDS

  // Epilogue. D mapping col=lane&15, row=(lane>>4)*4+reg (verified m89).
  // Wave-private LDS bounce (aliases dead ring) -> bf16x8 coalesced stores.
  __bf16* bnc = sm + wid * 16 * BST;
  const int q4 = (lane >> 4) * 4;
  const int row0 = tm0 + wr * 64;
  const int wn = tn0 + wc * 64;
  float bcol[4];
#pragma unroll
  for (int n = 0; n < 4; ++n) bcol[n] = BIAS ? bias[wn + n * 16 + lr] : 0.f;
#pragma unroll
  for (int m = 0; m < 4; ++m) {
    float ri[4];
    if constexpr (RSCALE) {
#pragma unroll
      for (int r = 0; r < 4; ++r)
        ri[r] = rowinv[(size_t)bz * 4096 + row0 + m * 16 + q4 + r];
    }
#pragma unroll
    for (int n = 0; n < 4; ++n)
#pragma unroll
      for (int r = 0; r < 4; ++r) {
        float val = acc[m][n][r] * scale + bcol[n];
        if constexpr (EEXP) val = exp2f(val * 1.44269504f);
        if constexpr (RSCALE) val *= ri[r];
        bnc[(q4 + r) * BST + n * 16 + lr] = (__bf16)val;
      }
    const int rr = lane >> 3, c8 = (lane & 7) * 8;
    bf16x8 v0 = *(const bf16x8*)&bnc[rr * BST + c8];
    bf16x8 v1 = *(const bf16x8*)&bnc[(rr + 8) * BST + c8];
    __bf16* op = Out + (size_t)bz * sO +
                 (size_t)(row0 + m * 16 + rr) * ldo + wn + c8;
    *(bf16x8*)op = v0;
    *(bf16x8*)(op + (size_t)8 * ldo) = v1;
  }
}

// ---------------------------------------------------------------------------
// 2-phase 128x128 GEMM (skinny shapes: v-proj, out-proj).
// EPI: 0 = bf16 out, 1 = f32 out, 2 = f32 out * xmul(bf16). BIAS: 0/1(col)/2(row).
// ---------------------------------------------------------------------------
template <int EPI, int BIAS>
__global__ __launch_bounds__(256) void gemm_lds_kernel(
    const __bf16* __restrict__ A, int lda, long long sA,
    const __bf16* __restrict__ Bm, int ldb, long long sB,
    void* __restrict__ Out, int ldo, long long sO,
    const float* __restrict__ bias, const __bf16* __restrict__ xmul,
    long long sX, float scale, int K) {
  __shared__ __bf16 sTa[2][128 * 32];
  __shared__ __bf16 sTb[2][128 * 32];

  const int gx = gridDim.x, gxy = gx * gridDim.y;
  const int nwg = gxy * gridDim.z;
  int bid = blockIdx.x + gx * blockIdx.y + gxy * blockIdx.z;
  if ((nwg & 7) == 0) bid = (bid & 7) * (nwg >> 3) + (bid >> 3);
  const int bz = bid / gxy;
  const int rem = bid - bz * gxy;
  const int by = rem / gx;
  const int bx = rem - by * gx;

  const int tid = threadIdx.x;
  const int lane = tid & 63;
  const int wid = tid >> 6;
  const int wr = wid >> 1, wc = wid & 1;
  const int tm0 = by * 128, tn0 = bx * 128;
  const int lr = lane & 15, lk = (lane >> 4) * 8;

  const int ch0 = wid * 2;
  const int srow = lane >> 2;
  const int scol = (lane & 3) * 8;
  const __bf16* gA0 = A + (size_t)bz * sA + (size_t)(tm0 + ch0 * 16 + srow) * lda + scol;
  const __bf16* gB0 = Bm + (size_t)bz * sB + (size_t)(tn0 + ch0 * 16 + srow) * ldb + scol;
  const size_t stepA = (size_t)16 * lda, stepB = (size_t)16 * ldb;

  f32x4 acc[4][4];
#pragma unroll
  for (int i = 0; i < 4; ++i)
#pragma unroll
    for (int j = 0; j < 4; ++j) acc[i][j] = f32x4{0.f, 0.f, 0.f, 0.f};

  const int T = K >> 5;
  gload_lds16(gA0, &sTa[0][ch0 * 512]);
  gload_lds16(gA0 + stepA, &sTa[0][ch0 * 512 + 512]);
  gload_lds16(gB0, &sTb[0][ch0 * 512]);
  gload_lds16(gB0 + stepB, &sTb[0][ch0 * 512 + 512]);

  for (int tt = 0; tt < T; ++tt) {
    __syncthreads();
    const int cur = tt & 1;
    if (tt + 1 < T) {
      const __bf16* a = gA0 + (size_t)(tt + 1) * 32;
      const __bf16* b = gB0 + (size_t)(tt + 1) * 32;
      gload_lds16(a, &sTa[cur ^ 1][ch0 * 512]);
      gload_lds16(a + stepA, &sTa[cur ^ 1][ch0 * 512 + 512]);
      gload_lds16(b, &sTb[cur ^ 1][ch0 * 512]);
      gload_lds16(b + stepB, &sTb[cur ^ 1][ch0 * 512 + 512]);
    }
    const __bf16* fa = &sTa[cur][(wr * 64 + lr) * 32 + lk];
    const __bf16* fb = &sTb[cur][(wc * 64 + lr) * 32 + lk];
    bf16x8 a[4], b[4];
#pragma unroll
    for (int i = 0; i < 4; ++i) a[i] = *(const bf16x8*)(fa + i * 512);
#pragma unroll
    for (int j = 0; j < 4; ++j) b[j] = *(const bf16x8*)(fb + j * 512);
#pragma unroll
    for (int i = 0; i < 4; ++i)
#pragma unroll
      for (int j = 0; j < 4; ++j)
        acc[i][j] = __builtin_amdgcn_mfma_f32_16x16x32_bf16(a[i], b[j], acc[i][j], 0, 0, 0);
  }

  const int wm = tm0 + wr * 64, wn = tn0 + wc * 64;
#pragma unroll
  for (int i = 0; i < 4; ++i) {
#pragma unroll
    for (int r = 0; r < 4; ++r) {
      const int row = wm + i * 16 + (lane >> 4) * 4 + r;
#pragma unroll
      for (int j = 0; j < 4; ++j) {
        const int col = wn + j * 16 + lr;
        float val = acc[i][j][r] * scale;
        if (BIAS == 1) val += bias[col];
        if (BIAS == 2) val += bias[row];
        const size_t off = (size_t)bz * sO + (size_t)row * ldo + col;
        if (EPI == 0) {
          ((__bf16*)Out)[off] = (__bf16)val;
        } else if (EPI == 1) {
          ((float*)Out)[off] = val;
        } else {
          ((float*)Out)[off] = (float)xmul[(size_t)bz * sX + (size_t)row * ldo + col] * val;
        }
      }
    }
  }
}

// ---------------------------------------------------------------------------
// Workspace (batched ~194 MiB):
//   S 128MB @0 (hnT aliases first 16) | qkT 32MB @128 (a2T alias) | v @160
//   xbf @176 | wB @192 | misc @194. rowInv (64 KB f32) lives in d_out
//   scratch, overwritten by the final out-proj.
// ---------------------------------------------------------------------------
extern "C" void kernel_launch(void* const* d_in, const int* in_sizes, int n_in,
                              void* d_out, int out_size, void* d_ws, size_t ws_size,
                              hipStream_t stream) {
  const int C = 512, N = 4096;
  const float* x = (const float*)d_in[0];
  const float* gng = (const float*)d_in[1];
  const float* gnb = (const float*)d_in[2];
  const float* wq = (const float*)d_in[3];
  const float* bq = (const float*)d_in[4];
  const float* wk = (const float*)d_in[5];
  const float* bk = (const float*)d_in[6];
  const float* wv = (const float*)d_in[7];
  const float* bv = (const float*)d_in[8];
  const float* wo = (const float*)d_in[9];
  const float* bo = (const float*)d_in[10];

  char* ws = (char*)d_ws;
  const size_t MB = 1ull << 20;
  const long long NC = (long long)N * C;
  const long long NN = (long long)N * N;
  const long long NQK = (long long)N * 1024;
  const bool batched = ws_size >= 194 * MB + 32768;

  __bf16 *S, *qkT, *a2T, *v, *xbf, *wqB;
  char* misc;
  if (batched) {
    S   = (__bf16*)(ws);
    qkT = (__bf16*)(ws + 128 * MB);
    a2T = qkT;
    v   = (__bf16*)(ws + 160 * MB);
    xbf = (__bf16*)(ws + 176 * MB);
    wqB = (__bf16*)(ws + 192 * MB);
    misc = ws + 194 * MB;
  } else {
    S   = (__bf16*)(ws);
    qkT = (__bf16*)(ws + 32 * MB);
    a2T = (__bf16*)(ws + 64 * MB);
    v   = (__bf16*)(ws + 80 * MB);
    xbf = (__bf16*)(ws + 96 * MB);
    wqB = (__bf16*)(ws + 112 * MB);
    misc = ws + 114 * MB;
  }
  __bf16* hnT = (__bf16*)ws;  // aliases S; dead before QK writes S
  __bf16* wvB = wqB + 2 * 262144;
  __bf16* woB = wvB + 262144;
  float* bqk   = (float*)misc;
  float2* gmbt = (float2*)(misc + 4096);
  float2* part = (float2*)(misc + 20480);
  float* rowInv = (float*)d_out;  // scratch in d_out, overwritten at the end

  const float scl = 0.044194173824159216f;  // 512^-0.5

  cvt4_kernel<<<4096, 256, 0, stream>>>(wq, wk, wv, wo, wqB);
  biascat_kernel<<<4, 256, 0, stream>>>(bq, bk, bqk);
  gn1a_kernel<<<1024, 256, 0, stream>>>(x, xbf, part);
  gn1b_kernel<<<4, 512, 0, stream>>>(part, gng, gnb, gmbt);
  gn2_kernel<<<dim3(64, 8, 4), 256, 0, stream>>>(xbf, gmbt, hnT);

  // fused q,k projection: qkT[b,n,0:512]=q, [512:1024]=k
  gemm4w_kernel<1, 0, 0, 512><<<dim3(8, 32, 4), 256, 0, stream>>>(
      hnT, C, NC, wqB, C, 0, qkT, 1024, NQK, bqk, nullptr, 1.f);
  // v[b,c,n]
  gemm_lds_kernel<0, 2><<<dim3(32, 4, 4), 256, 0, stream>>>(
      wvB, C, 0, hnT, C, NC, v, N, NC, bv, nullptr, 0, 1.f, C);

  if (batched) {
    // QK: S = exp(scl * q.k)  (unnormalized softmax numerator, bf16)
    gemm4w_kernel<0, 1, 0, 512><<<dim3(32, 32, 4), 256, 0, stream>>>(
        qkT, 1024, NQK, qkT + 512, 1024, NQK, S, N, NN, nullptr, nullptr, scl);
    rowsum_inv_kernel<<<4096, 256, 0, stream>>>(S, rowInv);
    // PV: a2T[i,c] = inv[i] * sum_j S[i,j] * v[c,j]
    gemm4w_kernel<0, 0, 1, 4096><<<dim3(4, 32, 4), 256, 0, stream>>>(
        S, N, NN, v, N, NC, a2T, C, NC, nullptr, rowInv, 1.f);
  } else {
    for (int b = 0; b < 4; ++b) {
      gemm4w_kernel<0, 1, 0, 512><<<dim3(32, 32, 1), 256, 0, stream>>>(
          qkT + (size_t)b * NQK, 1024, 0, qkT + (size_t)b * NQK + 512, 1024, 0,
          S, N, 0, nullptr, nullptr, scl);
      rowsum_inv_kernel<<<1024, 256, 0, stream>>>(S, rowInv);
      gemm4w_kernel<0, 0, 1, 4096><<<dim3(4, 32, 1), 256, 0, stream>>>(
          S, N, 0, v + (size_t)b * NC, N, 0, a2T + (size_t)b * NC, C, 0,
          nullptr, rowInv, 1.f);
    }
  }

  // out[b,c,n] = xbf[b,c,n] * (sum_k wo[c,k] * a2T[b,n,k] + bo[c])
  gemm_lds_kernel<2, 2><<<dim3(32, 4, 4), 256, 0, stream>>>(
      woB, C, 0, a2T, C, NC, (float*)d_out, N, NC, bo, xbf, NC, 1.f, C);
}

// Round 10
// 271.622 us; speedup vs baseline: 1.1163x; 1.0645x over previous
//
#include <hip/hip_runtime.h>
#include <hip/hip_bf16.h>
#include <stdint.h>

typedef __bf16 bf16x8 __attribute__((ext_vector_type(8)));
typedef __bf16 bf16x4 __attribute__((ext_vector_type(4)));
typedef float f32x4 __attribute__((ext_vector_type(4)));

__device__ __forceinline__ void gload_lds16(const __bf16* g, __bf16* l) {
  __builtin_amdgcn_global_load_lds(
      (const __attribute__((address_space(1))) void*)g,
      (__attribute__((address_space(3))) void*)l, 16, 0, 0);
}

// ---------------------------------------------------------------------------
// fp32 -> bf16 convert for the 4 weight matrices (contiguous dst)
// ---------------------------------------------------------------------------
__global__ __launch_bounds__(256) void cvt4_kernel(const float* __restrict__ s0,
                                                   const float* __restrict__ s1,
                                                   const float* __restrict__ s2,
                                                   const float* __restrict__ s3,
                                                   __bf16* __restrict__ dst) {
  int i = blockIdx.x * 256 + threadIdx.x;
  const float* srcs[4] = {s0, s1, s2, s3};
  int m = i >> 18;
  dst[i] = (__bf16)srcs[m][i & 262143];
}

__global__ __launch_bounds__(256) void biascat_kernel(const float* __restrict__ bq,
                                                      const float* __restrict__ bk,
                                                      float* __restrict__ bqk) {
  int i = blockIdx.x * 256 + threadIdx.x;  // 1024
  bqk[i] = (i < 512) ? bq[i] : bk[i - 512];
}

// ---------------------------------------------------------------------------
// GN1a: stream x fp32 once; write xbf + per-(b,g,slice) partial sums.
// ---------------------------------------------------------------------------
__global__ __launch_bounds__(256) void gn1a_kernel(const float* __restrict__ x,
                                                   __bf16* __restrict__ xbf,
                                                   float2* __restrict__ part) {
  const int tid = threadIdx.x;
  const size_t base4 = ((size_t)blockIdx.x * 8192) >> 2;
  const float4* x4 = (const float4*)x;
  bf16x4* o4 = (bf16x4*)xbf;

  float s1 = 0.f, s2 = 0.f;
#pragma unroll
  for (int j = 0; j < 8; ++j) {
    float4 t = x4[base4 + tid + j * 256];
    s1 += t.x + t.y + t.z + t.w;
    s2 += t.x * t.x + t.y * t.y + t.z * t.z + t.w * t.w;
    bf16x4 o;
    o[0] = (__bf16)t.x; o[1] = (__bf16)t.y; o[2] = (__bf16)t.z; o[3] = (__bf16)t.w;
    o4[base4 + tid + j * 256] = o;
  }
#pragma unroll
  for (int off = 32; off; off >>= 1) {
    s1 += __shfl_xor(s1, off);
    s2 += __shfl_xor(s2, off);
  }
  __shared__ float r1[4], r2[4];
  if ((tid & 63) == 0) { r1[tid >> 6] = s1; r2[tid >> 6] = s2; }
  __syncthreads();
  if (tid == 0)
    part[blockIdx.x] = float2{r1[0] + r1[1] + r1[2] + r1[3],
                              r2[0] + r2[1] + r2[2] + r2[3]};
}

__global__ __launch_bounds__(512) void gn1b_kernel(const float2* __restrict__ part,
                                                   const float* __restrict__ gamma,
                                                   const float* __restrict__ beta,
                                                   float2* __restrict__ gmbt) {
  const int b = blockIdx.x;
  const int t = threadIdx.x;
  __shared__ float sm[32], si[32];
  if (t < 32) {
    float s1 = 0.f, s2 = 0.f;
#pragma unroll
    for (int j = 0; j < 8; ++j) {
      float2 p = part[(b * 32 + t) * 8 + j];
      s1 += p.x; s2 += p.y;
    }
    const float mean = s1 * (1.f / 65536.f);
    const float var = s2 * (1.f / 65536.f) - mean * mean;
    sm[t] = mean;
    si[t] = rsqrtf(var + 1e-6f);
  }
  __syncthreads();
  const int g = t >> 4;
  const float gm = gamma[t] * si[g];
  gmbt[b * 512 + t] = float2{gm, beta[t] - sm[g] * gm};
}

// ---------------------------------------------------------------------------
// GN2: normalize + transpose. xbf [b,c,n] -> hnT [b,n,c] bf16.
// ---------------------------------------------------------------------------
__global__ __launch_bounds__(256) void gn2_kernel(const __bf16* __restrict__ xbf,
                                                  const float2* __restrict__ gmbt,
                                                  __bf16* __restrict__ hnT) {
  const int b = blockIdx.z;
  const int c0 = blockIdx.y * 64;
  const int n0 = blockIdx.x * 64;
  const int t = threadIdx.x;
  __shared__ __bf16 tile[64][72];

  {
    const int row = t >> 2;
    const int col = (t & 3) * 16;
    const __bf16* src = xbf + ((size_t)(b * 512 + c0 + row)) * 4096 + n0 + col;
    bf16x8 u0 = *(const bf16x8*)src;
    bf16x8 u1 = *(const bf16x8*)(src + 8);
    *(bf16x8*)&tile[row][col] = u0;
    *(bf16x8*)&tile[row][col + 8] = u1;
  }
  __syncthreads();
  {
    const int nrow = t >> 2;
    const int cc = (t & 3) * 16;
    bf16x8 o0, o1;
#pragma unroll
    for (int j = 0; j < 16; ++j) {
      const int c = c0 + cc + j;
      float2 s = gmbt[b * 512 + c];
      float val = (float)tile[cc + j][nrow] * s.x + s.y;
      if (j < 8) o0[j] = (__bf16)val; else o1[j - 8] = (__bf16)val;
    }
    __bf16* dst = hnT + ((size_t)b * 4096 + n0 + nrow) * 512 + c0 + cc;
    *(bf16x8*)dst = o0;
    *(bf16x8*)(dst + 8) = o1;
  }
}

// ---------------------------------------------------------------------------
// 8-phase 8-wave MFMA GEMM engine (T1+T2+T3+T4+T5) — r4 structure with r7's
// peel fix and the r4 SCALAR-store epilogue (measured fastest: 99.8 µs).
// D[m,n] = f( scale * sum_k A[m,k]*B[n,k] ); bf16 in/out, f32 acc.
// BM=256, BN=256, BK=64 (2 k-slots of 32), ring of 4 LDS slots/operand,
// 8 waves (2x4). EEXP: D = exp(val) (no-max softmax numerator; scores
// bounded ~N(0,1)). BIAS: + bias[col].
// Peel ledger: vmcnt 4/2/0 with vmcnt(0) BEFORE mmaPh(3,0) (slot-3 B read).
// Requires M%256==0, N%256==0, KC%128==0, grid multiple of 8.
// ---------------------------------------------------------------------------
template <int BN, int BIAS, int EEXP, int KC>
__global__ __launch_bounds__(512) void gemm8p_kernel(
    const __bf16* __restrict__ A, int lda, long long sA,
    const __bf16* __restrict__ Bm, int ldb, long long sB,
    __bf16* __restrict__ Out, int ldo, long long sO,
    const float* __restrict__ bias, float scale) {
  constexpr int NF = BN / 64;    // n-frags per wave
  constexpr int NH = NF / 2;     // n-frags per phase
  constexpr int BSLOT = BN * 32;
  constexpr int WN = BN / 4;     // wave n-width
  __shared__ __bf16 sm[4 * 8192 + 4 * BSLOT];
  __bf16* smB = sm + 4 * 8192;

  // T1: XCD-chunked swizzle (grids are multiples of 8)
  const int gx = gridDim.x, gxy = gx * gridDim.y;
  const int nwg = gxy * gridDim.z;
  int bid = blockIdx.x + gx * blockIdx.y + gxy * blockIdx.z;
  bid = (bid & 7) * (nwg >> 3) + (bid >> 3);
  const int bz = bid / gxy;
  const int rem = bid - bz * gxy;
  const int by = rem / gx, bx = rem - by * gx;
  const int tm0 = by * 256, tn0 = bx * BN;

  const int t = threadIdx.x;
  const int lane = t & 63, wid = t >> 6;
  const int wr = wid >> 2, wc = wid & 3;

  const __bf16* Az = A + (size_t)bz * sA;
  const __bf16* Bz = Bm + (size_t)bz * sB;

  // staging sources (pre-swizzled col so linear LDS + swizzled read = identity)
  const int scol = ((t & 3) * 8) ^ (((t >> 3) & 3) * 8);
  const __bf16* gA0 = Az + (size_t)(tm0 + (t >> 2)) * lda + scol;
  const __bf16* gA1 = gA0 + (size_t)128 * lda;
  const __bf16* gB0 = Bz + (size_t)(tn0 + (t >> 2)) * ldb + scol;
  const __bf16* gB1 = gB0 + (size_t)128 * ldb;
  __bf16* dA = sm + t * 8;
  __bf16* dB = smB + t * 8;

  auto stageA = [&](int ks) {
    const int sl = ks & 3;
    gload_lds16(gA0 + ks * 32, dA + sl * 8192);
    gload_lds16(gA1 + ks * 32, dA + sl * 8192 + 4096);
  };
  auto stageB = [&](int ks) {
    const int sl = ks & 3;
    gload_lds16(gB0 + ks * 32, dB + sl * BSLOT);
    if constexpr (BN == 256) gload_lds16(gB1 + ks * 32, dB + sl * BSLOT + 4096);
  };
  auto vmw = [&] {
    if constexpr (BN == 256) asm volatile("s_waitcnt vmcnt(8)" ::: "memory");
    else                     asm volatile("s_waitcnt vmcnt(6)" ::: "memory");
  };

  // swizzled fragment read bases
  const int lr = lane & 15;
  const int kb = ((lane >> 4) * 16) ^ ((lr & 6) << 3);  // byte off within row
  const __bf16* rdA = sm + (((wr * 128 + lr) * 64 + kb) >> 1);
  const __bf16* rdB = smB + (((wc * WN + lr) * 64 + kb) >> 1);

  f32x4 acc[8][NF];
#pragma unroll
  for (int m = 0; m < 8; ++m)
#pragma unroll
    for (int n = 0; n < NF; ++n) acc[m][n] = f32x4{0.f, 0.f, 0.f, 0.f};
  bf16x8 av[8];

  auto rdAfr = [&](int sl) {
#pragma unroll
    for (int m = 0; m < 8; ++m)
      av[m] = *(const bf16x8*)(rdA + sl * 8192 + m * 512);
  };
  auto mmaPh = [&](int sl, int nh) {
    bf16x8 bv[NH];
#pragma unroll
    for (int j = 0; j < NH; ++j)
      bv[j] = *(const bf16x8*)(rdB + sl * BSLOT + (nh * NH + j) * 512);
    __builtin_amdgcn_s_barrier();
    __builtin_amdgcn_s_setprio(1);
#pragma unroll
    for (int m = 0; m < 8; ++m)
#pragma unroll
      for (int j = 0; j < NH; ++j)
        acc[m][nh * NH + j] = __builtin_amdgcn_mfma_f32_16x16x32_bf16(
            av[m], bv[j], acc[m][nh * NH + j], 0, 0, 0);
    __builtin_amdgcn_s_setprio(0);
    __builtin_amdgcn_s_barrier();
  };

  constexpr int TOT = KC / 32;   // total k-slots
  constexpr int NIT = TOT / 4;   // ring iterations

  // prologue: stage slots 0,1,2; vmw ensures slot 0 landed
  stageA(0); stageB(0); stageA(1); stageB(1); stageA(2); stageB(2);
  vmw();
  __builtin_amdgcn_s_barrier();

  for (int it = 0; it < NIT - 1; ++it) {
    const int s3 = 4 * it + 3;
    rdAfr(0); stageA(s3);          mmaPh(0, 0);
    stageB(s3); vmw();             mmaPh(0, 1);
    rdAfr(1); stageA(s3 + 1);      mmaPh(1, 0);
    stageB(s3 + 1); vmw();         mmaPh(1, 1);
    rdAfr(2); stageA(s3 + 2);      mmaPh(2, 0);
    stageB(s3 + 2); vmw();         mmaPh(2, 1);
    rdAfr(3); stageA(s3 + 3);      mmaPh(3, 0);
    stageB(s3 + 3); vmw();         mmaPh(3, 1);
  }
  {  // peeled last iteration: strict ledger; vmcnt(0) guards slot-3 B at (3,0)
    const int s3 = TOT - 1;
    rdAfr(0); stageA(s3);          mmaPh(0, 0);
    stageB(s3); vmw();             mmaPh(0, 1);
    rdAfr(1);                      mmaPh(1, 0);
    if constexpr (BN == 256) asm volatile("s_waitcnt vmcnt(4)" ::: "memory");
    else                     asm volatile("s_waitcnt vmcnt(3)" ::: "memory");
    mmaPh(1, 1);
    rdAfr(2);                      mmaPh(2, 0);
    if constexpr (BN == 256) asm volatile("s_waitcnt vmcnt(2)" ::: "memory");
    else                     asm volatile("s_waitcnt vmcnt(1)" ::: "memory");
    mmaPh(2, 1);
    rdAfr(3);
    asm volatile("s_waitcnt vmcnt(0)" ::: "memory");
    mmaPh(3, 0);
    mmaPh(3, 1);
  }

  // Epilogue: r4's scalar-store pattern (measured fastest for this engine).
  // D mapping col=lane&15, row=(lane>>4)*4+reg (verified m89).
  const int q4 = (lane >> 4) * 4;
  const int wnb = tn0 + wc * WN;
  float bcol[NF];
#pragma unroll
  for (int n = 0; n < NF; ++n) bcol[n] = BIAS ? bias[wnb + n * 16 + lr] : 0.f;
#pragma unroll
  for (int m = 0; m < 8; ++m) {
#pragma unroll
    for (int r = 0; r < 4; ++r) {
      const int row = tm0 + wr * 128 + m * 16 + q4 + r;
      __bf16* orow = Out + (size_t)bz * sO + (size_t)row * ldo + wnb + lr;
#pragma unroll
      for (int n = 0; n < NF; ++n) {
        float val = acc[m][n][r] * scale + bcol[n];
        if constexpr (EEXP) val = exp2f(val * 1.44269504f);
        orow[n * 16] = (__bf16)val;
      }
    }
  }
}

// ---------------------------------------------------------------------------
// gemm4w: 4-wave 128x128 MFMA engine — counted-vmcnt ring-4 + T2 swizzle +
// 2 resident blocks/CU (64 KiB LDS).
// D[m,n] = f( scale * sum_k A[m,k]*B[n,k] ); bf16 in/out, f32 acc.
// RSUM: per slot, one extra MFMA per A-frag against a ones-B accumulates the
//   exact row sums of A (= P row sums) into acc1 — same D-register layout as
//   the output rows, so the epilogue applies D *= 1/acc1 with no cross-lane
//   traffic. Replaces the standalone rowsum_inv pass (21 µs + 134 MB HBM).
// BIAS: + bias[col]. Ledger: 4 loads/slot, lookahead 3; steady vmcnt(8),
// tail 4/0. Requires M%128==0, N%128==0, KC%32==0, KC/32>=4, grid %8==0.
// ---------------------------------------------------------------------------
template <int BIAS, int RSUM, int KC>
__global__ __launch_bounds__(256) void gemm4w_kernel(
    const __bf16* __restrict__ A, int lda, long long sA,
    const __bf16* __restrict__ Bm, int ldb, long long sB,
    __bf16* __restrict__ Out, int ldo, long long sO,
    const float* __restrict__ bias, float scale) {
  constexpr int SLOT = 4096;   // 128x32 elems
  constexpr int BST = 72;      // bounce row stride
  __shared__ __bf16 sm[8 * SLOT];  // 64 KiB: A ring [0..4), B ring [4..8)
  __bf16* smB = sm + 4 * SLOT;

  // T1: XCD-chunked swizzle
  const int gx = gridDim.x, gxy = gx * gridDim.y;
  const int nwg = gxy * gridDim.z;
  int bid = blockIdx.x + gx * blockIdx.y + gxy * blockIdx.z;
  bid = (bid & 7) * (nwg >> 3) + (bid >> 3);
  const int bz = bid / gxy;
  const int rem = bid - bz * gxy;
  const int by = rem / gx, bx = rem - by * gx;
  const int tm0 = by * 128, tn0 = bx * 128;

  const int t = threadIdx.x;
  const int lane = t & 63, wid = t >> 6;
  const int wr = wid >> 1, wc = wid & 1;

  const __bf16* Az = A + (size_t)bz * sA;
  const __bf16* Bz = Bm + (size_t)bz * sB;

  // staging: thread t covers row t>>2 (+64 on 2nd pass), pre-swizzled chunk
  const int scol = ((t & 3) * 8) ^ (((t >> 3) & 3) * 8);
  const __bf16* gA0 = Az + (size_t)(tm0 + (t >> 2)) * lda + scol;
  const __bf16* gA1 = gA0 + (size_t)64 * lda;
  const __bf16* gB0 = Bz + (size_t)(tn0 + (t >> 2)) * ldb + scol;
  const __bf16* gB1 = gB0 + (size_t)64 * ldb;
  __bf16* dA = sm + t * 8;
  __bf16* dB = smB + t * 8;

  auto stage = [&](int ks) {
    const int sl = ks & 3;
    gload_lds16(gA0 + (size_t)ks * 32, dA + sl * SLOT);
    gload_lds16(gA1 + (size_t)ks * 32, dA + sl * SLOT + 2048);
    gload_lds16(gB0 + (size_t)ks * 32, dB + sl * SLOT);
    gload_lds16(gB1 + (size_t)ks * 32, dB + sl * SLOT + 2048);
  };

  // swizzled fragment read bases (row stride 64 B)
  const int lr = lane & 15;
  const int kb = ((lane >> 4) * 16) ^ ((lr & 6) << 3);
  const __bf16* rdA = sm + (((wr * 64 + lr) * 64 + kb) >> 1);
  const __bf16* rdB = smB + (((wc * 64 + lr) * 64 + kb) >> 1);

  f32x4 acc[4][4];
#pragma unroll
  for (int i = 0; i < 4; ++i)
#pragma unroll
    for (int j = 0; j < 4; ++j) acc[i][j] = f32x4{0.f, 0.f, 0.f, 0.f};
  f32x4 acc1[4];
#pragma unroll
  for (int i = 0; i < 4; ++i) acc1[i] = f32x4{0.f, 0.f, 0.f, 0.f};
  bf16x8 onesf;
#pragma unroll
  for (int e = 0; e < 8; ++e) onesf[e] = (__bf16)1.0f;

  bf16x8 av[4], bv[4];

  auto rdfr = [&](int sl) {
#pragma unroll
    for (int m = 0; m < 4; ++m) av[m] = *(const bf16x8*)(rdA + sl * SLOT + m * 512);
#pragma unroll
    for (int n = 0; n < 4; ++n) bv[n] = *(const bf16x8*)(rdB + sl * SLOT + n * 512);
  };
  auto mma16 = [&] {
    __builtin_amdgcn_s_barrier();
    __builtin_amdgcn_s_setprio(1);
#pragma unroll
    for (int m = 0; m < 4; ++m)
#pragma unroll
      for (int n = 0; n < 4; ++n)
        acc[m][n] = __builtin_amdgcn_mfma_f32_16x16x32_bf16(av[m], bv[n], acc[m][n], 0, 0, 0);
    if constexpr (RSUM) {
#pragma unroll
      for (int m = 0; m < 4; ++m)
        acc1[m] = __builtin_amdgcn_mfma_f32_16x16x32_bf16(av[m], onesf, acc1[m], 0, 0, 0);
    }
    __builtin_amdgcn_s_setprio(0);
  };

  constexpr int TOT = KC / 32;  // >= 4

  // prologue: stage slots 0,1,2 (12 loads); vmcnt(8) -> slot 0 complete
  stage(0); stage(1); stage(2);
  asm volatile("s_waitcnt vmcnt(8)" ::: "memory");
  __builtin_amdgcn_s_barrier();

#pragma unroll 1
  for (int s = 0; s < TOT - 3; ++s) {
    rdfr(s & 3);
    stage(s + 3);
    mma16();
    asm volatile("s_waitcnt vmcnt(8)" ::: "memory");
    __builtin_amdgcn_s_barrier();
  }
  // tail: 3 slots left, ledger 4 / 0 / -
  rdfr((TOT - 3) & 3); mma16();
  asm volatile("s_waitcnt vmcnt(4)" ::: "memory");
  __builtin_amdgcn_s_barrier();
  rdfr((TOT - 2) & 3); mma16();
  asm volatile("s_waitcnt vmcnt(0)" ::: "memory");
  __builtin_amdgcn_s_barrier();
  rdfr((TOT - 1) & 3); mma16();
  __builtin_amdgcn_s_barrier();  // ring reads done before bounce aliases LDS

  // Epilogue. D mapping col=lane&15, row=(lane>>4)*4+reg (verified m89).
  // Wave-private LDS bounce (aliases dead ring) -> bf16x8 coalesced stores.
  __bf16* bnc = sm + wid * 16 * BST;
  const int q4 = (lane >> 4) * 4;
  const int row0 = tm0 + wr * 64;
  const int wn = tn0 + wc * 64;
  float bcol[4];
#pragma unroll
  for (int n = 0; n < 4; ++n) bcol[n] = BIAS ? bias[wn + n * 16 + lr] : 0.f;
#pragma unroll
  for (int m = 0; m < 4; ++m) {
    float ri[4];
    if constexpr (RSUM) {
#pragma unroll
      for (int r = 0; r < 4; ++r) ri[r] = 1.0f / acc1[m][r];
    }
#pragma unroll
    for (int n = 0; n < 4; ++n)
#pragma unroll
      for (int r = 0; r < 4; ++r) {
        float val = acc[m][n][r] * scale + bcol[n];
        if constexpr (RSUM) val *= ri[r];
        bnc[(q4 + r) * BST + n * 16 + lr] = (__bf16)val;
      }
    const int rr = lane >> 3, c8 = (lane & 7) * 8;
    bf16x8 v0 = *(const bf16x8*)&bnc[rr * BST + c8];
    bf16x8 v1 = *(const bf16x8*)&bnc[(rr + 8) * BST + c8];
    __bf16* op = Out + (size_t)bz * sO +
                 (size_t)(row0 + m * 16 + rr) * ldo + wn + c8;
    *(bf16x8*)op = v0;
    *(bf16x8*)(op + (size_t)8 * ldo) = v1;
  }
}

// ---------------------------------------------------------------------------
// 2-phase 128x128 GEMM (skinny shapes: v-proj, out-proj).
// EPI: 0 = bf16 out, 1 = f32 out, 2 = f32 out * xmul(bf16). BIAS: 0/1(col)/2(row).
// ---------------------------------------------------------------------------
template <int EPI, int BIAS>
__global__ __launch_bounds__(256) void gemm_lds_kernel(
    const __bf16* __restrict__ A, int lda, long long sA,
    const __bf16* __restrict__ Bm, int ldb, long long sB,
    void* __restrict__ Out, int ldo, long long sO,
    const float* __restrict__ bias, const __bf16* __restrict__ xmul,
    long long sX, float scale, int K) {
  __shared__ __bf16 sTa[2][128 * 32];
  __shared__ __bf16 sTb[2][128 * 32];

  const int gx = gridDim.x, gxy = gx * gridDim.y;
  const int nwg = gxy * gridDim.z;
  int bid = blockIdx.x + gx * blockIdx.y + gxy * blockIdx.z;
  if ((nwg & 7) == 0) bid = (bid & 7) * (nwg >> 3) + (bid >> 3);
  const int bz = bid / gxy;
  const int rem = bid - bz * gxy;
  const int by = rem / gx;
  const int bx = rem - by * gx;

  const int tid = threadIdx.x;
  const int lane = tid & 63;
  const int wid = tid >> 6;
  const int wr = wid >> 1, wc = wid & 1;
  const int tm0 = by * 128, tn0 = bx * 128;
  const int lr = lane & 15, lk = (lane >> 4) * 8;

  const int ch0 = wid * 2;
  const int srow = lane >> 2;
  const int scol = (lane & 3) * 8;
  const __bf16* gA0 = A + (size_t)bz * sA + (size_t)(tm0 + ch0 * 16 + srow) * lda + scol;
  const __bf16* gB0 = Bm + (size_t)bz * sB + (size_t)(tn0 + ch0 * 16 + srow) * ldb + scol;
  const size_t stepA = (size_t)16 * lda, stepB = (size_t)16 * ldb;

  f32x4 acc[4][4];
#pragma unroll
  for (int i = 0; i < 4; ++i)
#pragma unroll
    for (int j = 0; j < 4; ++j) acc[i][j] = f32x4{0.f, 0.f, 0.f, 0.f};

  const int T = K >> 5;
  gload_lds16(gA0, &sTa[0][ch0 * 512]);
  gload_lds16(gA0 + stepA, &sTa[0][ch0 * 512 + 512]);
  gload_lds16(gB0, &sTb[0][ch0 * 512]);
  gload_lds16(gB0 + stepB, &sTb[0][ch0 * 512 + 512]);

  for (int tt = 0; tt < T; ++tt) {
    __syncthreads();
    const int cur = tt & 1;
    if (tt + 1 < T) {
      const __bf16* a = gA0 + (size_t)(tt + 1) * 32;
      const __bf16* b = gB0 + (size_t)(tt + 1) * 32;
      gload_lds16(a, &sTa[cur ^ 1][ch0 * 512]);
      gload_lds16(a + stepA, &sTa[cur ^ 1][ch0 * 512 + 512]);
      gload_lds16(b, &sTb[cur ^ 1][ch0 * 512]);
      gload_lds16(b + stepB, &sTb[cur ^ 1][ch0 * 512 + 512]);
    }
    const __bf16* fa = &sTa[cur][(wr * 64 + lr) * 32 + lk];
    const __bf16* fb = &sTb[cur][(wc * 64 + lr) * 32 + lk];
    bf16x8 a[4], b[4];
#pragma unroll
    for (int i = 0; i < 4; ++i) a[i] = *(const bf16x8*)(fa + i * 512);
#pragma unroll
    for (int j = 0; j < 4; ++j) b[j] = *(const bf16x8*)(fb + j * 512);
#pragma unroll
    for (int i = 0; i < 4; ++i)
#pragma unroll
      for (int j = 0; j < 4; ++j)
        acc[i][j] = __builtin_amdgcn_mfma_f32_16x16x32_bf16(a[i], b[j], acc[i][j], 0, 0, 0);
  }

  const int wm = tm0 + wr * 64, wn = tn0 + wc * 64;
#pragma unroll
  for (int i = 0; i < 4; ++i) {
#pragma unroll
    for (int r = 0; r < 4; ++r) {
      const int row = wm + i * 16 + (lane >> 4) * 4 + r;
#pragma unroll
      for (int j = 0; j < 4; ++j) {
        const int col = wn + j * 16 + lr;
        float val = acc[i][j][r] * scale;
        if (BIAS == 1) val += bias[col];
        if (BIAS == 2) val += bias[row];
        const size_t off = (size_t)bz * sO + (size_t)row * ldo + col;
        if (EPI == 0) {
          ((__bf16*)Out)[off] = (__bf16)val;
        } else if (EPI == 1) {
          ((float*)Out)[off] = val;
        } else {
          ((float*)Out)[off] = (float)xmul[(size_t)bz * sX + (size_t)row * ldo + col] * val;
        }
      }
    }
  }
}

// ---------------------------------------------------------------------------
// Workspace (batched ~194 MiB):
//   S 128MB @0 (hnT aliases first 16) | qkT 32MB @128 (a2T alias) | v @160
//   xbf @176 | wB @192 | misc @194. No d_out scratch needed anymore (PV
//   computes its own row sums via ones-MFMA).
// ---------------------------------------------------------------------------
extern "C" void kernel_launch(void* const* d_in, const int* in_sizes, int n_in,
                              void* d_out, int out_size, void* d_ws, size_t ws_size,
                              hipStream_t stream) {
  const int C = 512, N = 4096;
  const float* x = (const float*)d_in[0];
  const float* gng = (const float*)d_in[1];
  const float* gnb = (const float*)d_in[2];
  const float* wq = (const float*)d_in[3];
  const float* bq = (const float*)d_in[4];
  const float* wk = (const float*)d_in[5];
  const float* bk = (const float*)d_in[6];
  const float* wv = (const float*)d_in[7];
  const float* bv = (const float*)d_in[8];
  const float* wo = (const float*)d_in[9];
  const float* bo = (const float*)d_in[10];

  char* ws = (char*)d_ws;
  const size_t MB = 1ull << 20;
  const long long NC = (long long)N * C;
  const long long NN = (long long)N * N;
  const long long NQK = (long long)N * 1024;
  const bool batched = ws_size >= 194 * MB + 32768;

  __bf16 *S, *qkT, *a2T, *v, *xbf, *wqB;
  char* misc;
  if (batched) {
    S   = (__bf16*)(ws);
    qkT = (__bf16*)(ws + 128 * MB);
    a2T = qkT;
    v   = (__bf16*)(ws + 160 * MB);
    xbf = (__bf16*)(ws + 176 * MB);
    wqB = (__bf16*)(ws + 192 * MB);
    misc = ws + 194 * MB;
  } else {
    S   = (__bf16*)(ws);
    qkT = (__bf16*)(ws + 32 * MB);
    a2T = (__bf16*)(ws + 64 * MB);
    v   = (__bf16*)(ws + 80 * MB);
    xbf = (__bf16*)(ws + 96 * MB);
    wqB = (__bf16*)(ws + 112 * MB);
    misc = ws + 114 * MB;
  }
  __bf16* hnT = (__bf16*)ws;  // aliases S; dead before QK writes S
  __bf16* wvB = wqB + 2 * 262144;
  __bf16* woB = wvB + 262144;
  float* bqk   = (float*)misc;
  float2* gmbt = (float2*)(misc + 4096);
  float2* part = (float2*)(misc + 20480);

  const float scl = 0.044194173824159216f;  // 512^-0.5

  cvt4_kernel<<<4096, 256, 0, stream>>>(wq, wk, wv, wo, wqB);
  biascat_kernel<<<4, 256, 0, stream>>>(bq, bk, bqk);
  gn1a_kernel<<<1024, 256, 0, stream>>>(x, xbf, part);
  gn1b_kernel<<<4, 512, 0, stream>>>(part, gng, gnb, gmbt);
  gn2_kernel<<<dim3(64, 8, 4), 256, 0, stream>>>(xbf, gmbt, hnT);

  // fused q,k projection: qkT[b,n,0:512]=q, [512:1024]=k
  gemm4w_kernel<1, 0, 512><<<dim3(8, 32, 4), 256, 0, stream>>>(
      hnT, C, NC, wqB, C, 0, qkT, 1024, NQK, bqk, 1.f);
  // v[b,c,n]
  gemm_lds_kernel<0, 2><<<dim3(32, 4, 4), 256, 0, stream>>>(
      wvB, C, 0, hnT, C, NC, v, N, NC, bv, nullptr, 0, 1.f, C);

  if (batched) {
    // QK: S = exp(scl * q.k)  (unnormalized softmax numerator, bf16)
    gemm8p_kernel<256, 0, 1, 512><<<dim3(16, 16, 4), 512, 0, stream>>>(
        qkT, 1024, NQK, qkT + 512, 1024, NQK, S, N, NN, nullptr, scl);
    // PV: a2T[i,c] = (1/rowsum_i) * sum_j S[i,j] * v[c,j]; rowsum fused
    gemm4w_kernel<0, 1, 4096><<<dim3(4, 32, 4), 256, 0, stream>>>(
        S, N, NN, v, N, NC, a2T, C, NC, nullptr, 1.f);
  } else {
    for (int b = 0; b < 4; ++b) {
      gemm8p_kernel<256, 0, 1, 512><<<dim3(16, 16, 1), 512, 0, stream>>>(
          qkT + (size_t)b * NQK, 1024, 0, qkT + (size_t)b * NQK + 512, 1024, 0,
          S, N, 0, nullptr, scl);
      gemm4w_kernel<0, 1, 4096><<<dim3(4, 32, 1), 256, 0, stream>>>(
          S, N, 0, v + (size_t)b * NC, N, 0, a2T + (size_t)b * NC, C, 0,
          nullptr, 1.f);
    }
  }

  // out[b,c,n] = xbf[b,c,n] * (sum_k wo[c,k] * a2T[b,n,k] + bo[c])
  gemm_lds_kernel<2, 2><<<dim3(32, 4, 4), 256, 0, stream>>>(
      woB, C, 0, a2T, C, NC, (float*)d_out, N, NC, bo, xbf, NC, 1.f, C);
}

// Round 11
// 264.158 us; speedup vs baseline: 1.1478x; 1.0283x over previous
//
#include <hip/hip_runtime.h>
#include <hip/hip_bf16.h>
#include <stdint.h>

typedef __bf16 bf16x8 __attribute__((ext_vector_type(8)));
typedef __bf16 bf16x4 __attribute__((ext_vector_type(4)));
typedef float f32x4 __attribute__((ext_vector_type(4)));

__device__ __forceinline__ void gload_lds16(const __bf16* g, __bf16* l) {
  __builtin_amdgcn_global_load_lds(
      (const __attribute__((address_space(1))) void*)g,
      (__attribute__((address_space(3))) void*)l, 16, 0, 0);
}

// ---------------------------------------------------------------------------
// fp32 -> bf16 convert for the 4 weight matrices (contiguous dst)
// ---------------------------------------------------------------------------
__global__ __launch_bounds__(256) void cvt4_kernel(const float* __restrict__ s0,
                                                   const float* __restrict__ s1,
                                                   const float* __restrict__ s2,
                                                   const float* __restrict__ s3,
                                                   __bf16* __restrict__ dst) {
  int i = blockIdx.x * 256 + threadIdx.x;
  const float* srcs[4] = {s0, s1, s2, s3};
  int m = i >> 18;
  dst[i] = (__bf16)srcs[m][i & 262143];
}

__global__ __launch_bounds__(256) void biascat_kernel(const float* __restrict__ bq,
                                                      const float* __restrict__ bk,
                                                      float* __restrict__ bqk) {
  int i = blockIdx.x * 256 + threadIdx.x;  // 1024
  bqk[i] = (i < 512) ? bq[i] : bk[i - 512];
}

// ---------------------------------------------------------------------------
// GN1a: stream x fp32 once; write xbf + per-(b,g,slice) partial sums.
// ---------------------------------------------------------------------------
__global__ __launch_bounds__(256) void gn1a_kernel(const float* __restrict__ x,
                                                   __bf16* __restrict__ xbf,
                                                   float2* __restrict__ part) {
  const int tid = threadIdx.x;
  const size_t base4 = ((size_t)blockIdx.x * 8192) >> 2;
  const float4* x4 = (const float4*)x;
  bf16x4* o4 = (bf16x4*)xbf;

  float s1 = 0.f, s2 = 0.f;
#pragma unroll
  for (int j = 0; j < 8; ++j) {
    float4 t = x4[base4 + tid + j * 256];
    s1 += t.x + t.y + t.z + t.w;
    s2 += t.x * t.x + t.y * t.y + t.z * t.z + t.w * t.w;
    bf16x4 o;
    o[0] = (__bf16)t.x; o[1] = (__bf16)t.y; o[2] = (__bf16)t.z; o[3] = (__bf16)t.w;
    o4[base4 + tid + j * 256] = o;
  }
#pragma unroll
  for (int off = 32; off; off >>= 1) {
    s1 += __shfl_xor(s1, off);
    s2 += __shfl_xor(s2, off);
  }
  __shared__ float r1[4], r2[4];
  if ((tid & 63) == 0) { r1[tid >> 6] = s1; r2[tid >> 6] = s2; }
  __syncthreads();
  if (tid == 0)
    part[blockIdx.x] = float2{r1[0] + r1[1] + r1[2] + r1[3],
                              r2[0] + r2[1] + r2[2] + r2[3]};
}

__global__ __launch_bounds__(512) void gn1b_kernel(const float2* __restrict__ part,
                                                   const float* __restrict__ gamma,
                                                   const float* __restrict__ beta,
                                                   float2* __restrict__ gmbt) {
  const int b = blockIdx.x;
  const int t = threadIdx.x;
  __shared__ float sm[32], si[32];
  if (t < 32) {
    float s1 = 0.f, s2 = 0.f;
#pragma unroll
    for (int j = 0; j < 8; ++j) {
      float2 p = part[(b * 32 + t) * 8 + j];
      s1 += p.x; s2 += p.y;
    }
    const float mean = s1 * (1.f / 65536.f);
    const float var = s2 * (1.f / 65536.f) - mean * mean;
    sm[t] = mean;
    si[t] = rsqrtf(var + 1e-6f);
  }
  __syncthreads();
  const int g = t >> 4;
  const float gm = gamma[t] * si[g];
  gmbt[b * 512 + t] = float2{gm, beta[t] - sm[g] * gm};
}

// ---------------------------------------------------------------------------
// GN2: normalize + transpose. xbf [b,c,n] -> hnT [b,n,c] bf16.
// ---------------------------------------------------------------------------
__global__ __launch_bounds__(256) void gn2_kernel(const __bf16* __restrict__ xbf,
                                                  const float2* __restrict__ gmbt,
                                                  __bf16* __restrict__ hnT) {
  const int b = blockIdx.z;
  const int c0 = blockIdx.y * 64;
  const int n0 = blockIdx.x * 64;
  const int t = threadIdx.x;
  __shared__ __bf16 tile[64][72];

  {
    const int row = t >> 2;
    const int col = (t & 3) * 16;
    const __bf16* src = xbf + ((size_t)(b * 512 + c0 + row)) * 4096 + n0 + col;
    bf16x8 u0 = *(const bf16x8*)src;
    bf16x8 u1 = *(const bf16x8*)(src + 8);
    *(bf16x8*)&tile[row][col] = u0;
    *(bf16x8*)&tile[row][col + 8] = u1;
  }
  __syncthreads();
  {
    const int nrow = t >> 2;
    const int cc = (t & 3) * 16;
    bf16x8 o0, o1;
#pragma unroll
    for (int j = 0; j < 16; ++j) {
      const int c = c0 + cc + j;
      float2 s = gmbt[b * 512 + c];
      float val = (float)tile[cc + j][nrow] * s.x + s.y;
      if (j < 8) o0[j] = (__bf16)val; else o1[j - 8] = (__bf16)val;
    }
    __bf16* dst = hnT + ((size_t)b * 4096 + n0 + nrow) * 512 + c0 + cc;
    *(bf16x8*)dst = o0;
    *(bf16x8*)(dst + 8) = o1;
  }
}

// ---------------------------------------------------------------------------
// qkexp: PERSISTENT QK kernel. S[b, i, j] = exp(scale * q_i . k_j), bf16.
// Grid (16, 4, gz): block covers 1024 rows (4 subtiles of 256) x 256 cols.
// One grid round (256 blocks); continuous ring-4 across subtile boundaries —
// NO vmcnt(0) drains. Ledger (in-order VMEM retirement): wait-N = #ops issued
// after the target slot's 4 loads. Steady: 8. For the 2 iterations after a
// subtile epilogue (16 bounce stores): 24. Tail s=61/62: 4/0.
// Epilogue: per-wave DEDICATED LDS bounce (not aliased; ring stays live) ->
// exactly 16 bf16x8 global stores per thread. B-panel identical across
// subtiles -> re-staged from hot L2.
// ---------------------------------------------------------------------------
__global__ __launch_bounds__(512) void qkexp_kernel(
    const __bf16* __restrict__ q, const __bf16* __restrict__ k,
    __bf16* __restrict__ S, long long sQ, long long sS, float scale) {
  constexpr int BST = 72;
  __shared__ __bf16 sm[8 * 8192 + 8 * 16 * BST];  // A ring | B ring | bounce
  __bf16* smB = sm + 4 * 8192;
  __bf16* smE = sm + 8 * 8192;

  // T1: XCD-chunked swizzle (nwg multiple of 8)
  const int gx = gridDim.x, gxy = gx * gridDim.y;
  const int nwg = gxy * gridDim.z;
  int bid = blockIdx.x + gx * blockIdx.y + gxy * blockIdx.z;
  bid = (bid & 7) * (nwg >> 3) + (bid >> 3);
  const int bz = bid / gxy;
  const int rem = bid - bz * gxy;
  const int by = rem / gx, bx = rem - by * gx;
  const int tm0 = by * 1024, tn0 = bx * 256;

  const int t = threadIdx.x;
  const int lane = t & 63, wid = t >> 6;
  const int wr = wid >> 2, wc = wid & 3;

  // staging sources (pre-swizzled col; lda = ldb = 1024)
  const int scol = ((t & 3) * 8) ^ (((t >> 3) & 3) * 8);
  const __bf16* gA0 = q + (size_t)bz * sQ + (size_t)(tm0 + (t >> 2)) * 1024 + scol;
  const __bf16* gA1 = gA0 + (size_t)128 * 1024;
  const __bf16* gB0 = k + (size_t)bz * sQ + (size_t)(tn0 + (t >> 2)) * 1024 + scol;
  const __bf16* gB1 = gB0 + (size_t)128 * 1024;
  __bf16* dA = sm + t * 8;
  __bf16* dB = smB + t * 8;

  auto stageA = [&](int sig) {
    const int st_ = sig >> 4, ks = sig & 15, sl = sig & 3;
    const size_t off = (size_t)(st_ * 256) * 1024 + ks * 32;
    gload_lds16(gA0 + off, dA + sl * 8192);
    gload_lds16(gA1 + off, dA + sl * 8192 + 4096);
  };
  auto stageB = [&](int sig) {
    const int ks = sig & 15, sl = sig & 3;
    gload_lds16(gB0 + ks * 32, dB + sl * 8192);
    gload_lds16(gB1 + ks * 32, dB + sl * 8192 + 4096);
  };

  // swizzled fragment read bases (row stride 64 B)
  const int lr = lane & 15;
  const int kb = ((lane >> 4) * 16) ^ ((lr & 6) << 3);
  const __bf16* rdA = sm + (((wr * 128 + lr) * 64 + kb) >> 1);
  const __bf16* rdB = smB + (((wc * 64 + lr) * 64 + kb) >> 1);

  f32x4 acc[8][4];
#pragma unroll
  for (int m = 0; m < 8; ++m)
#pragma unroll
    for (int n = 0; n < 4; ++n) acc[m][n] = f32x4{0.f, 0.f, 0.f, 0.f};
  bf16x8 av[8];

  auto rdAfr = [&](int sl) {
#pragma unroll
    for (int m = 0; m < 8; ++m)
      av[m] = *(const bf16x8*)(rdA + sl * 8192 + m * 512);
  };
  auto mmaPh = [&](int sl, int nh) {
    bf16x8 bv[2];
#pragma unroll
    for (int j = 0; j < 2; ++j)
      bv[j] = *(const bf16x8*)(rdB + sl * 8192 + (nh * 2 + j) * 512);
    __builtin_amdgcn_s_barrier();
    __builtin_amdgcn_s_setprio(1);
#pragma unroll
    for (int m = 0; m < 8; ++m)
#pragma unroll
      for (int j = 0; j < 2; ++j)
        acc[m][nh * 2 + j] = __builtin_amdgcn_mfma_f32_16x16x32_bf16(
            av[m], bv[j], acc[m][nh * 2 + j], 0, 0, 0);
    __builtin_amdgcn_s_setprio(0);
    __builtin_amdgcn_s_barrier();
  };

  // epilogue(st): D mapping col=lane&15, row=(lane>>4)*4+reg (verified m89).
  // Dedicated wave-private bounce -> 16 bf16x8 stores per thread.
  __bf16* bnc = smE + wid * 16 * BST;
  const int q4 = (lane >> 4) * 4;
  auto epilogue = [&](int st) {
    const int row0 = tm0 + st * 256 + wr * 128;
    const int wn = tn0 + wc * 64;
#pragma unroll
    for (int m = 0; m < 8; ++m) {
#pragma unroll
      for (int n = 0; n < 4; ++n)
#pragma unroll
        for (int r = 0; r < 4; ++r) {
          float val = acc[m][n][r] * scale;
          val = exp2f(val * 1.44269504f);
          bnc[(q4 + r) * BST + n * 16 + lr] = (__bf16)val;
        }
      const int rr = lane >> 3, c8 = (lane & 7) * 8;
      bf16x8 v0 = *(const bf16x8*)&bnc[rr * BST + c8];
      bf16x8 v1 = *(const bf16x8*)&bnc[(rr + 8) * BST + c8];
      __bf16* op = S + (size_t)bz * sS +
                   (size_t)(row0 + m * 16 + rr) * 4096 + wn + c8;
      *(bf16x8*)op = v0;
      *(bf16x8*)(op + (size_t)8 * 4096) = v1;
    }
  };

  // prologue: stage slots 0,1,2 (12 loads); vmcnt(8) -> slot 0 complete
  stageA(0); stageB(0); stageA(1); stageB(1); stageA(2); stageB(2);
  asm volatile("s_waitcnt vmcnt(8)" ::: "memory");
  __builtin_amdgcn_s_barrier();

#pragma unroll 1
  for (int s = 0; s < 64; ++s) {
    const int sl = s & 3;
    rdAfr(sl);
    if (s + 3 < 64) stageA(s + 3);
    mmaPh(sl, 0);
    if (s + 3 < 64) stageB(s + 3);
    // wait guaranteeing slot s+1 resident (in-order retirement ledger)
    if (s >= 61) {
      if (s == 61) asm volatile("s_waitcnt vmcnt(4)" ::: "memory");
      else if (s == 62) asm volatile("s_waitcnt vmcnt(0)" ::: "memory");
    } else if ((s & 15) <= 1 && s > 15) {
      asm volatile("s_waitcnt vmcnt(24)" ::: "memory");  // +16 epilogue stores
    } else {
      asm volatile("s_waitcnt vmcnt(8)" ::: "memory");
    }
    mmaPh(sl, 1);
    if ((s & 15) == 15) {
      epilogue(s >> 4);
      if (s < 63) {
#pragma unroll
        for (int m = 0; m < 8; ++m)
#pragma unroll
          for (int n = 0; n < 4; ++n) acc[m][n] = f32x4{0.f, 0.f, 0.f, 0.f};
      }
    }
  }
}

// ---------------------------------------------------------------------------
// gemm4w: 4-wave 128x128 MFMA engine — counted-vmcnt ring-4 + T2 swizzle +
// 2 resident blocks/CU (64 KiB LDS).
// D[m,n] = f( scale * sum_k A[m,k]*B[n,k] ); f32 acc.
// RSUM: ones-B MFMA accumulates exact row sums of A into acc1 (same D-reg
//   layout) -> epilogue scales by 1/rowsum (softmax denominator, fused).
// BIASMODE: 0 none, 1 col, 2 row. EPI: 0 bf16 out (LDS-bounce vector stores),
//   2 f32 out * xmul[row,col] (scalar stores).
// Ledger: 4 loads/slot, lookahead 3; steady vmcnt(8), tail 4/0.
// Requires M%128==0, N%128==0, KC%32==0, KC/32>=4, grid %8==0.
// ---------------------------------------------------------------------------
template <int BIASMODE, int RSUM, int EPI, int KC>
__global__ __launch_bounds__(256) void gemm4w_kernel(
    const __bf16* __restrict__ A, int lda, long long sA,
    const __bf16* __restrict__ Bm, int ldb, long long sB,
    void* __restrict__ Out, int ldo, long long sO,
    const float* __restrict__ bias, const __bf16* __restrict__ xmul,
    long long sX, float scale) {
  constexpr int SLOT = 4096;   // 128x32 elems
  constexpr int BST = 72;      // bounce row stride
  __shared__ __bf16 sm[8 * SLOT];  // 64 KiB: A ring [0..4), B ring [4..8)
  __bf16* smB = sm + 4 * SLOT;

  // T1: XCD-chunked swizzle
  const int gx = gridDim.x, gxy = gx * gridDim.y;
  const int nwg = gxy * gridDim.z;
  int bid = blockIdx.x + gx * blockIdx.y + gxy * blockIdx.z;
  bid = (bid & 7) * (nwg >> 3) + (bid >> 3);
  const int bz = bid / gxy;
  const int rem = bid - bz * gxy;
  const int by = rem / gx, bx = rem - by * gx;
  const int tm0 = by * 128, tn0 = bx * 128;

  const int t = threadIdx.x;
  const int lane = t & 63, wid = t >> 6;
  const int wr = wid >> 1, wc = wid & 1;

  const __bf16* Az = A + (size_t)bz * sA;
  const __bf16* Bz = Bm + (size_t)bz * sB;

  const int scol = ((t & 3) * 8) ^ (((t >> 3) & 3) * 8);
  const __bf16* gA0 = Az + (size_t)(tm0 + (t >> 2)) * lda + scol;
  const __bf16* gA1 = gA0 + (size_t)64 * lda;
  const __bf16* gB0 = Bz + (size_t)(tn0 + (t >> 2)) * ldb + scol;
  const __bf16* gB1 = gB0 + (size_t)64 * ldb;
  __bf16* dA = sm + t * 8;
  __bf16* dB = smB + t * 8;

  auto stage = [&](int ks) {
    const int sl = ks & 3;
    gload_lds16(gA0 + (size_t)ks * 32, dA + sl * SLOT);
    gload_lds16(gA1 + (size_t)ks * 32, dA + sl * SLOT + 2048);
    gload_lds16(gB0 + (size_t)ks * 32, dB + sl * SLOT);
    gload_lds16(gB1 + (size_t)ks * 32, dB + sl * SLOT + 2048);
  };

  const int lr = lane & 15;
  const int kb = ((lane >> 4) * 16) ^ ((lr & 6) << 3);
  const __bf16* rdA = sm + (((wr * 64 + lr) * 64 + kb) >> 1);
  const __bf16* rdB = smB + (((wc * 64 + lr) * 64 + kb) >> 1);

  f32x4 acc[4][4];
#pragma unroll
  for (int i = 0; i < 4; ++i)
#pragma unroll
    for (int j = 0; j < 4; ++j) acc[i][j] = f32x4{0.f, 0.f, 0.f, 0.f};
  f32x4 acc1[4];
#pragma unroll
  for (int i = 0; i < 4; ++i) acc1[i] = f32x4{0.f, 0.f, 0.f, 0.f};
  bf16x8 onesf;
#pragma unroll
  for (int e = 0; e < 8; ++e) onesf[e] = (__bf16)1.0f;

  bf16x8 av[4], bv[4];

  auto rdfr = [&](int sl) {
#pragma unroll
    for (int m = 0; m < 4; ++m) av[m] = *(const bf16x8*)(rdA + sl * SLOT + m * 512);
#pragma unroll
    for (int n = 0; n < 4; ++n) bv[n] = *(const bf16x8*)(rdB + sl * SLOT + n * 512);
  };
  auto mma16 = [&] {
    __builtin_amdgcn_s_barrier();
    __builtin_amdgcn_s_setprio(1);
#pragma unroll
    for (int m = 0; m < 4; ++m)
#pragma unroll
      for (int n = 0; n < 4; ++n)
        acc[m][n] = __builtin_amdgcn_mfma_f32_16x16x32_bf16(av[m], bv[n], acc[m][n], 0, 0, 0);
    if constexpr (RSUM) {
#pragma unroll
      for (int m = 0; m < 4; ++m)
        acc1[m] = __builtin_amdgcn_mfma_f32_16x16x32_bf16(av[m], onesf, acc1[m], 0, 0, 0);
    }
    __builtin_amdgcn_s_setprio(0);
  };

  constexpr int TOT = KC / 32;  // >= 4

  stage(0); stage(1); stage(2);
  asm volatile("s_waitcnt vmcnt(8)" ::: "memory");
  __builtin_amdgcn_s_barrier();

#pragma unroll 1
  for (int s = 0; s < TOT - 3; ++s) {
    rdfr(s & 3);
    stage(s + 3);
    mma16();
    asm volatile("s_waitcnt vmcnt(8)" ::: "memory");
    __builtin_amdgcn_s_barrier();
  }
  rdfr((TOT - 3) & 3); mma16();
  asm volatile("s_waitcnt vmcnt(4)" ::: "memory");
  __builtin_amdgcn_s_barrier();
  rdfr((TOT - 2) & 3); mma16();
  asm volatile("s_waitcnt vmcnt(0)" ::: "memory");
  __builtin_amdgcn_s_barrier();
  rdfr((TOT - 1) & 3); mma16();
  __builtin_amdgcn_s_barrier();  // ring reads done before bounce aliases LDS

  // Epilogue. D mapping col=lane&15, row=(lane>>4)*4+reg (verified m89).
  const int q4 = (lane >> 4) * 4;
  const int row0 = tm0 + wr * 64;
  const int wn = tn0 + wc * 64;
  if constexpr (EPI == 0) {
    __bf16* bnc = sm + wid * 16 * BST;  // aliases dead ring
#pragma unroll
    for (int m = 0; m < 4; ++m) {
      float ri[4];
      if constexpr (RSUM) {
#pragma unroll
        for (int r = 0; r < 4; ++r) ri[r] = 1.0f / acc1[m][r];
      }
#pragma unroll
      for (int n = 0; n < 4; ++n)
#pragma unroll
        for (int r = 0; r < 4; ++r) {
          float val = acc[m][n][r] * scale;
          if constexpr (BIASMODE == 1) val += bias[wn + n * 16 + lr];
          if constexpr (BIASMODE == 2) val += bias[row0 + m * 16 + q4 + r];
          if constexpr (RSUM) val *= ri[r];
          bnc[(q4 + r) * BST + n * 16 + lr] = (__bf16)val;
        }
      const int rr = lane >> 3, c8 = (lane & 7) * 8;
      bf16x8 v0 = *(const bf16x8*)&bnc[rr * BST + c8];
      bf16x8 v1 = *(const bf16x8*)&bnc[(rr + 8) * BST + c8];
      __bf16* op = (__bf16*)Out + (size_t)bz * sO +
                   (size_t)(row0 + m * 16 + rr) * ldo + wn + c8;
      *(bf16x8*)op = v0;
      *(bf16x8*)(op + (size_t)8 * ldo) = v1;
    }
  } else {  // EPI == 2: f32 out * xmul, scalar stores
#pragma unroll
    for (int m = 0; m < 4; ++m) {
#pragma unroll
      for (int r = 0; r < 4; ++r) {
        const int row = row0 + m * 16 + q4 + r;
        float brow = (BIASMODE == 2) ? bias[row] : 0.f;
        const size_t base = (size_t)bz * sO + (size_t)row * ldo;
#pragma unroll
        for (int n = 0; n < 4; ++n) {
          const int col = wn + n * 16 + lr;
          float val = acc[m][n][r] * scale + brow;
          if constexpr (BIASMODE == 1) val += bias[col];
          ((float*)Out)[base + col] =
              (float)xmul[(size_t)bz * sX + (size_t)row * ldo + col] * val;
        }
      }
    }
  }
}

// ---------------------------------------------------------------------------
// Workspace (batched ~194 MiB):
//   S 128MB @0 (hnT aliases first 16) | qkT 32MB @128 (a2T alias) | v @160
//   xbf @176 | wB @192 | misc @194.
// ---------------------------------------------------------------------------
extern "C" void kernel_launch(void* const* d_in, const int* in_sizes, int n_in,
                              void* d_out, int out_size, void* d_ws, size_t ws_size,
                              hipStream_t stream) {
  const int C = 512, N = 4096;
  const float* x = (const float*)d_in[0];
  const float* gng = (const float*)d_in[1];
  const float* gnb = (const float*)d_in[2];
  const float* wq = (const float*)d_in[3];
  const float* bq = (const float*)d_in[4];
  const float* wk = (const float*)d_in[5];
  const float* bk = (const float*)d_in[6];
  const float* wv = (const float*)d_in[7];
  const float* bv = (const float*)d_in[8];
  const float* wo = (const float*)d_in[9];
  const float* bo = (const float*)d_in[10];

  char* ws = (char*)d_ws;
  const size_t MB = 1ull << 20;
  const long long NC = (long long)N * C;
  const long long NN = (long long)N * N;
  const long long NQK = (long long)N * 1024;
  const bool batched = ws_size >= 194 * MB + 32768;

  __bf16 *S, *qkT, *a2T, *v, *xbf, *wqB;
  char* misc;
  if (batched) {
    S   = (__bf16*)(ws);
    qkT = (__bf16*)(ws + 128 * MB);
    a2T = qkT;
    v   = (__bf16*)(ws + 160 * MB);
    xbf = (__bf16*)(ws + 176 * MB);
    wqB = (__bf16*)(ws + 192 * MB);
    misc = ws + 194 * MB;
  } else {
    S   = (__bf16*)(ws);
    qkT = (__bf16*)(ws + 32 * MB);
    a2T = (__bf16*)(ws + 64 * MB);
    v   = (__bf16*)(ws + 80 * MB);
    xbf = (__bf16*)(ws + 96 * MB);
    wqB = (__bf16*)(ws + 112 * MB);
    misc = ws + 114 * MB;
  }
  __bf16* hnT = (__bf16*)ws;  // aliases S; dead before QK writes S
  __bf16* wvB = wqB + 2 * 262144;
  __bf16* woB = wvB + 262144;
  float* bqk   = (float*)misc;
  float2* gmbt = (float2*)(misc + 4096);
  float2* part = (float2*)(misc + 20480);

  const float scl = 0.044194173824159216f;  // 512^-0.5

  cvt4_kernel<<<4096, 256, 0, stream>>>(wq, wk, wv, wo, wqB);
  biascat_kernel<<<4, 256, 0, stream>>>(bq, bk, bqk);
  gn1a_kernel<<<1024, 256, 0, stream>>>(x, xbf, part);
  gn1b_kernel<<<4, 512, 0, stream>>>(part, gng, gnb, gmbt);
  gn2_kernel<<<dim3(64, 8, 4), 256, 0, stream>>>(xbf, gmbt, hnT);

  // fused q,k projection: qkT[b,n,0:512]=q, [512:1024]=k
  gemm4w_kernel<1, 0, 0, 512><<<dim3(8, 32, 4), 256, 0, stream>>>(
      hnT, C, NC, wqB, C, 0, qkT, 1024, NQK, bqk, nullptr, 0, 1.f);
  // v[b,c,n] = sum_k wv[c,k] hnT[n,k] + bv[c]  (row bias)
  gemm4w_kernel<2, 0, 0, 512><<<dim3(32, 4, 4), 256, 0, stream>>>(
      wvB, C, 0, hnT, C, NC, v, N, NC, bv, nullptr, 0, 1.f);

  if (batched) {
    // QK persistent: S = exp(scl * q.k), one grid round
    qkexp_kernel<<<dim3(16, 4, 4), 512, 0, stream>>>(
        qkT, qkT + 512, S, NQK, NN, scl);
    // PV: a2T[i,c] = (1/rowsum_i) * sum_j S[i,j] * v[c,j]; rowsum via ones-MFMA
    gemm4w_kernel<0, 1, 0, 4096><<<dim3(4, 32, 4), 256, 0, stream>>>(
        S, N, NN, v, N, NC, a2T, C, NC, nullptr, nullptr, 0, 1.f);
  } else {
    for (int b = 0; b < 4; ++b) {
      qkexp_kernel<<<dim3(16, 4, 1), 512, 0, stream>>>(
          qkT + (size_t)b * NQK, qkT + (size_t)b * NQK + 512, S, 0, 0, scl);
      gemm4w_kernel<0, 1, 0, 4096><<<dim3(4, 32, 1), 256, 0, stream>>>(
          S, N, 0, v + (size_t)b * NC, N, 0, a2T + (size_t)b * NC, C, 0,
          nullptr, nullptr, 0, 1.f);
    }
  }

  // out[b,c,n] = xbf[b,c,n] * (sum_k wo[c,k] * a2T[b,n,k] + bo[c])
  gemm4w_kernel<2, 0, 2, 512><<<dim3(32, 4, 4), 256, 0, stream>>>(
      woB, C, 0, a2T, C, NC, d_out, N, NC, bo, xbf, NC, 1.f);
}